// Round 12
// baseline (241.389 us; speedup 1.0000x reference)
//
#include <hip/hip_runtime.h>
#include <hip/hip_fp16.h>

#define NN 10000
#define DIN 128
#define HD 64
#define HH 128          // H*HEADS
#define NE 250000
#define NP 100000

// ---------------- CSR build ----------------

__global__ void count_kernel(const int* e12, const int* e21, int* cnt12, int* cnt21) {
    int t = blockIdx.x * blockDim.x + threadIdx.x;
    if (t < NE)            atomicAdd(&cnt12[e12[NE + t]], 1);
    else if (t < 2 * NE)   atomicAdd(&cnt21[e21[NE + (t - NE)]], 1);
}

__global__ void scan_kernel(const int* cnt12, const int* cnt21,
                            int* ptr12, int* ptr21, int* cur12, int* cur21) {
    const int* cnt = blockIdx.x ? cnt21 : cnt12;
    int* ptr = blockIdx.x ? ptr21 : ptr12;
    int* cur = blockIdx.x ? cur21 : cur12;
    const int T = 1024, C = 10;                 // 1024*10 = 10240 >= 10000
    __shared__ int sm[1024];
    int t = threadIdx.x;
    int v[C]; int tot = 0;
    int base = t * C;
    #pragma unroll
    for (int i = 0; i < C; i++) {
        int id = base + i;
        v[i] = (id < NN) ? cnt[id] : 0;
        tot += v[i];
    }
    sm[t] = tot; __syncthreads();
    for (int off = 1; off < T; off <<= 1) {
        int x = (t >= off) ? sm[t - off] : 0;
        __syncthreads();
        sm[t] += x;
        __syncthreads();
    }
    int run = sm[t] - tot;                      // exclusive prefix
    #pragma unroll
    for (int i = 0; i < C; i++) {
        int id = base + i;
        if (id < NN) { ptr[id] = run; cur[id] = run; }
        run += v[i];
    }
    if (t == T - 1) ptr[NN] = run;
}

// writes rows_sorted AND cols_sorted (dest of each CSR slot)
__global__ void fill_kernel(const int* e12, const int* e21,
                            int* cur12, int* cur21,
                            int* rs12, int* rs21, int* cs12, int* cs21) {
    int t = blockIdx.x * blockDim.x + threadIdx.x;
    if (t < NE) {
        int c = e12[NE + t];
        int p = atomicAdd(&cur12[c], 1);
        rs12[p] = e12[t];
        cs12[p] = c;
    } else if (t < 2 * NE) {
        int e = t - NE;
        int c = e21[NE + e];
        int p = atomicAdd(&cur21[c], 1);
        rs21[p] = e21[e];
        cs21[p] = c;
    }
}

// ---------------- input GEMM (weights staged in LDS) ----------------

__global__ void in_gemm(const float* __restrict__ xn1, const float* __restrict__ xn2,
                        const float* __restrict__ Win, const float* __restrict__ b_in,
                        float* x1, float* x2) {
    int z = blockIdx.z;
    const float4* A4 = (const float4*)(z ? xn2 : xn1);
    const float4* W4 = (const float4*)(Win + (size_t)z * DIN * HD);
    const float4* b4 = (const float4*)(b_in + (size_t)z * HD);
    float4* O4 = (float4*)(z ? x2 : x1);
    __shared__ float As[16 * DIN];              // 8 KB
    __shared__ float Ws[DIN * HD];              // 32 KB
    int tid = threadIdx.x;
    int row0 = blockIdx.x * 16;
    float4* As4 = (float4*)As;
    float4* Ws4 = (float4*)Ws;
    As4[tid]       = A4[(size_t)row0 * 32 + tid];
    As4[tid + 256] = A4[(size_t)row0 * 32 + tid + 256];
    #pragma unroll
    for (int i = 0; i < 8; i++) Ws4[tid + 256 * i] = W4[tid + 256 * i];
    __syncthreads();
    int r = tid >> 4, cg = tid & 15;
    float4 acc = b4[cg];
    const float* a = &As[r * DIN];
    for (int k = 0; k < DIN; k++) {
        float av = a[k];
        float4 w = Ws4[k * 16 + cg];
        acc.x += av * w.x; acc.y += av * w.y; acc.z += av * w.z; acc.w += av * w.w;
    }
    acc.x = fmaxf(acc.x, 0.f); acc.y = fmaxf(acc.y, 0.f);
    acc.z = fmaxf(acc.z, 0.f); acc.w = fmaxf(acc.w, 0.f);
    O4[(size_t)(row0 + r) * 16 + cg] = acc;
}

// ---------------- K/Q/V GEMM (weights staged in LDS) ----------------
// z in [0,6): rel = z/3, kind = z%3 (0=K 1=Q 2=V); outputs fp16 [rel][NN][128].
// block z==0,x==0 zeroes this layer's sum partials.
__global__ void kqv_gemm(const float* __restrict__ x1, const float* __restrict__ x2,
                         const float* __restrict__ Wk, const float* __restrict__ Wq,
                         const float* __restrict__ Wv,
                         const float* __restrict__ bk, const float* __restrict__ bq,
                         const float* __restrict__ bv,
                         __half* Kh, __half* Qh, __half* Vh, float* sums, int l) {
    int z = blockIdx.z;
    int rel = z / 3, kind = z - rel * 3;
    if (z == 0 && blockIdx.x == 0) sums[l * 256 + threadIdx.x] = 0.f;
    const float* xsrc = rel ? x2 : x1;
    const float* xdst = rel ? x1 : x2;
    const float* A = (kind == 1) ? xdst : xsrc;
    size_t wo = (size_t)(l * 2 + rel) * HD * HH;
    size_t bo = (size_t)(l * 2 + rel) * HH;
    const float4* W4 = (const float4*)((kind == 0 ? Wk : kind == 1 ? Wq : Wv) + wo);
    const float4* b4 = (const float4*)((kind == 0 ? bk : kind == 1 ? bq : bv) + bo);
    const float4* A4 = (const float4*)A;
    __shared__ float As[16 * HD];               // 4 KB
    __shared__ float Ws[HD * HH];               // 32 KB
    int tid = threadIdx.x;
    int row0 = blockIdx.x * 16;
    float4* As4 = (float4*)As;
    float4* Ws4 = (float4*)Ws;
    As4[tid] = A4[(size_t)row0 * 16 + tid];     // 16 rows x 16 float4
    #pragma unroll
    for (int i = 0; i < 8; i++) Ws4[tid + 256 * i] = W4[tid + 256 * i];
    __syncthreads();
    int cg = tid & 31, rg = tid >> 5;           // rg 0..7, rows rg*2, rg*2+1
    float4 acc0 = b4[cg], acc1 = acc0;
    const float* a0 = &As[(rg * 2) * HD];
    const float* a1 = &As[(rg * 2 + 1) * HD];
    for (int k = 0; k < HD; k++) {
        float4 w = Ws4[k * 32 + cg];
        float v0 = a0[k], v1 = a1[k];
        acc0.x += v0 * w.x; acc0.y += v0 * w.y; acc0.z += v0 * w.z; acc0.w += v0 * w.w;
        acc1.x += v1 * w.x; acc1.y += v1 * w.y; acc1.z += v1 * w.z; acc1.w += v1 * w.w;
    }
    __half* dst = (kind == 0) ? Kh : (kind == 1) ? Qh : Vh;
    int node = row0 + rg * 2;
    {
        __half2* H2 = (__half2*)(dst + (size_t)rel * NN * HH + (size_t)node * HH + cg * 4);
        float2 lo = {acc0.x, acc0.y}, hi = {acc0.z, acc0.w};
        H2[0] = __float22half2_rn(lo);
        H2[1] = __float22half2_rn(hi);
    }
    {
        __half2* H2 = (__half2*)(dst + (size_t)rel * NN * HH + (size_t)(node + 1) * HH + cg * 4);
        float2 lo = {acc1.x, acc1.y}, hi = {acc1.z, acc1.w};
        H2[0] = __float22half2_rn(lo);
        H2[1] = __float22half2_rn(hi);
    }
}

// ---------------- helpers ----------------

__device__ __forceinline__ float dotc(const uint4& k, const uint4& q) {
    const __half2* kh = (const __half2*)&k;
    const __half2* qh = (const __half2*)&q;
    float s = 0.f;
    #pragma unroll
    for (int i = 0; i < 4; i++) {
        float2 a = __half22float2(kh[i]);
        float2 b = __half22float2(qh[i]);
        s += a.x * b.x + a.y * b.y;
    }
    return s;
}
__device__ __forceinline__ void acc8(const uint4& v, float e, float* acc) {
    const __half2* h = (const __half2*)&v;
    float2 f0 = __half22float2(h[0]), f1 = __half22float2(h[1]);
    float2 f2 = __half22float2(h[2]), f3 = __half22float2(h[3]);
    acc[0] += e*f0.x; acc[1] += e*f0.y; acc[2] += e*f1.x; acc[3] += e*f1.y;
    acc[4] += e*f2.x; acc[5] += e*f2.y; acc[6] += e*f3.x; acc[7] += e*f3.y;
}

// ---------------- fused attention: block = (rel, 8 dest nodes) ----------------
// phase A: lane-per-edge logits over the block's CSR edge range -> ew (global),
//          block-reduced exp-sums -> 2 atomics/block.
// __syncthreads() makes the block's own ew writes visible.
// phase B: wave-per-node weighted-V gather (16 edges in flight), reads ew hot.
__global__ __launch_bounds__(256) void conv_fused(
        const int* __restrict__ ptr12, const int* __restrict__ rs12,
        const int* __restrict__ cs12,
        const int* __restrict__ ptr21, const int* __restrict__ rs21,
        const int* __restrict__ cs21,
        const __half* __restrict__ Kh, const __half* __restrict__ Qh,
        const __half* __restrict__ Vh,
        float* __restrict__ ew, float* __restrict__ aggb,
        float* __restrict__ sums, int l) {
    int b = blockIdx.x;
    int rel = b & 1, seg = b >> 1;              // seg in [0, 1250)
    const int* __restrict__ ptr = rel ? ptr21 : ptr12;
    const int* __restrict__ rs  = rel ? rs21 : rs12;
    const int* __restrict__ cs  = rel ? cs21 : cs12;
    const uint4* K = (const uint4*)(Kh + (size_t)rel * NN * HH);
    const uint4* Q = (const uint4*)(Qh + (size_t)rel * NN * HH);
    const uint4* V = (const uint4*)(Vh + (size_t)rel * NN * HH);
    float* __restrict__ ew0 = ew + (size_t)rel * 2 * NE;
    float* __restrict__ ew1 = ew0 + NE;
    float4* A4 = (float4*)(aggb + (size_t)rel * NN * HH);
    int tid = threadIdx.x;
    int c0 = seg * 8;
    int jb0 = ptr[c0], je0 = ptr[c0 + 8];

    // ---- phase A ----
    float s0 = 0.f, s1 = 0.f;
    for (int j = jb0 + tid; j < je0; j += 256) {
        int row = rs[j], col = cs[j];
        const uint4* kp = K + (size_t)row * 16;
        const uint4* qp = Q + (size_t)col * 16;
        float a0 = 0.f, a1 = 0.f;
        #pragma unroll
        for (int i = 0; i < 16; i += 4) {
            uint4 k0 = kp[i], k1 = kp[i + 1], k2 = kp[i + 2], k3 = kp[i + 3];
            uint4 q0 = qp[i], q1 = qp[i + 1], q2 = qp[i + 2], q3 = qp[i + 3];
            float ss = dotc(k0, q0) + dotc(k1, q1) + dotc(k2, q2) + dotc(k3, q3);
            if (i < 8) a0 += ss; else a1 += ss; // compile-time select
        }
        a0 *= 0.125f; a1 *= 0.125f;
        a0 = a0 > 0.f ? a0 : 0.2f * a0;
        a1 = a1 > 0.f ? a1 : 0.2f * a1;
        float e0 = __expf(a0);
        float e1 = __expf(a1);
        ew0[j] = e0; ew1[j] = e1;
        s0 += e0; s1 += e1;
    }
    __shared__ float sred[4][2];
    #pragma unroll
    for (int off = 1; off <= 32; off <<= 1) {
        s0 += __shfl_xor(s0, off);
        s1 += __shfl_xor(s1, off);
    }
    int wave = tid >> 6, lane = tid & 63;
    if (lane == 0) { sred[wave][0] = s0; sred[wave][1] = s1; }
    __syncthreads();                            // also publishes ew to the block
    if (tid < 2) {
        float t = sred[0][tid] + sred[1][tid] + sred[2][tid] + sred[3][tid];
        atomicAdd(&sums[l * 256 + rel * 128 + tid * 64 + (seg & 63)], t);
    }

    // ---- phase B: 4 waves x 2 nodes each ----
    int g = lane >> 4, sl = lane & 15;
    const float* __restrict__ wp = ew0 + (size_t)(sl >> 3) * NE;   // head plane
    #pragma unroll
    for (int ni = 0; ni < 2; ni++) {
        int c = c0 + wave * 2 + ni;
        float acc[8] = {0,0,0,0,0,0,0,0};
        int jb = ptr[c], je = ptr[c + 1];
        int o = jb + g;
        int r0 = (o      < je) ? rs[o]      : -1;
        int r1 = (o + 4  < je) ? rs[o + 4]  : -1;
        int r2 = (o + 8  < je) ? rs[o + 8]  : -1;
        int r3 = (o + 12 < je) ? rs[o + 12] : -1;
        for (int j = o; j < je; j += 16) {
            int n0 = (j + 16 < je) ? rs[j + 16] : -1;
            int n1 = (j + 20 < je) ? rs[j + 20] : -1;
            int n2 = (j + 24 < je) ? rs[j + 24] : -1;
            int n3 = (j + 28 < je) ? rs[j + 28] : -1;
            float w0 = (r0 >= 0) ? wp[j]      : 0.f;
            float w1 = (r1 >= 0) ? wp[j + 4]  : 0.f;
            float w2 = (r2 >= 0) ? wp[j + 8]  : 0.f;
            float w3 = (r3 >= 0) ? wp[j + 12] : 0.f;
            uint4 v0 = V[(size_t)(r0 >= 0 ? r0 : 0) * 16 + sl];
            uint4 v1 = V[(size_t)(r1 >= 0 ? r1 : 0) * 16 + sl];
            uint4 v2 = V[(size_t)(r2 >= 0 ? r2 : 0) * 16 + sl];
            uint4 v3 = V[(size_t)(r3 >= 0 ? r3 : 0) * 16 + sl];
            acc8(v0, w0, acc); acc8(v1, w1, acc);
            acc8(v2, w2, acc); acc8(v3, w3, acc);
            r0 = n0; r1 = n1; r2 = n2; r3 = n3;
        }
        #pragma unroll
        for (int i = 0; i < 8; i++) {
            acc[i] += __shfl_xor(acc[i], 16);
            acc[i] += __shfl_xor(acc[i], 32);
        }
        if (g == 0) {
            float4 t0 = {acc[0], acc[1], acc[2], acc[3]};
            float4 t1 = {acc[4], acc[5], acc[6], acc[7]};
            A4[(size_t)c * 32 + 2 * sl]     = t0;
            A4[(size_t)c * 32 + 2 * sl + 1] = t1;
        }
    }
}

// ---------------- out GEMM (softmax scale folded; W staged in LDS) ----------
__global__ void out_gemm(const float* __restrict__ aggb,
                         const float* __restrict__ Wout, const float* __restrict__ bout,
                         const float* __restrict__ sums, int l,
                         float* x1, float* x2, __half2* Emh2, __half2* Edh2) {
    int z = blockIdx.z;
    int sel = z ? 0 : 1;                        // which relation's aggregate
    const float4* A4 = (const float4*)(aggb + (size_t)sel * NN * HH);
    const float4* W4 = (const float4*)(Wout + (size_t)(l * 2 + z) * HH * HD);
    const float4* b4 = (const float4*)(bout + (size_t)(l * 2 + z) * HD);
    float4* X4 = (float4*)(z ? x2 : x1);
    __half2* E2 = z ? Edh2 : Emh2;
    __shared__ float As[16 * HH];               // 8 KB
    __shared__ float Ws[HH * HD];               // 32 KB
    __shared__ float invs[2];
    int tid = threadIdx.x;
    if (tid < 128) {
        int h = tid >> 6;
        float v = sums[l * 256 + sel * 128 + h * 64 + (tid & 63)];
        #pragma unroll
        for (int off = 1; off <= 32; off <<= 1) v += __shfl_xor(v, off);
        if ((tid & 63) == 0) invs[h] = 1.f / v;
    }
    __syncthreads();
    float inv0 = invs[0], inv1 = invs[1];
    int row0 = blockIdx.x * 16;
    float4* As4 = (float4*)As;
    float4* Ws4 = (float4*)Ws;
    {
        float4 t0 = A4[(size_t)row0 * 32 + tid];
        float4 t1 = A4[(size_t)row0 * 32 + tid + 256];
        float s0 = ((tid & 31) < 16) ? inv0 : inv1;   // cols 0-63 = head0
        t0.x *= s0; t0.y *= s0; t0.z *= s0; t0.w *= s0;
        t1.x *= s0; t1.y *= s0; t1.z *= s0; t1.w *= s0;
        As4[tid] = t0; As4[tid + 256] = t1;
    }
    #pragma unroll
    for (int i = 0; i < 8; i++) Ws4[tid + 256 * i] = W4[tid + 256 * i];
    __syncthreads();
    int r = tid >> 4, cg = tid & 15;
    float4 acc = b4[cg];
    const float* a = &As[r * HH];
    for (int k = 0; k < HH; k++) {
        float av = a[k];
        float4 w = Ws4[k * 16 + cg];
        acc.x += av * w.x; acc.y += av * w.y; acc.z += av * w.z; acc.w += av * w.w;
    }
    int node = row0 + r;
    X4[(size_t)node * 16 + cg] = acc;
    float2 lo = {acc.x, acc.y}, hi = {acc.z, acc.w};
    E2[(size_t)node * 64 + l * 32 + cg * 2]     = __float22half2_rn(lo);
    E2[(size_t)node * 64 + l * 32 + cg * 2 + 1] = __float22half2_rn(hi);
}

// ---------------- prediction (lane-per-pair, fp16 streaming) ----------------
__global__ __launch_bounds__(256) void pred_kernel(
        const __half* __restrict__ Emh, const __half* __restrict__ Edh,
        const int* __restrict__ pe, float* out) {
    int p = blockIdx.x * 256 + threadIdx.x;
    if (p >= NP) return;
    int m = pe[p], d = pe[NP + p];
    const uint4* a = (const uint4*)Emh + (size_t)m * 16;
    const uint4* b = (const uint4*)Edh + (size_t)d * 16;
    float acc = 0.f;
    #pragma unroll
    for (int i = 0; i < 16; i += 4) {
        uint4 a0 = a[i], a1 = a[i + 1], a2 = a[i + 2], a3 = a[i + 3];
        uint4 b0 = b[i], b1 = b[i + 1], b2 = b[i + 2], b3 = b[i + 3];
        acc += dotc(a0, b0) + dotc(a1, b1) + dotc(a2, b2) + dotc(a3, b3);
    }
    out[p] = acc;
}

// ---------------- host ----------------

extern "C" void kernel_launch(void* const* d_in, const int* in_sizes, int n_in,
                              void* d_out, int out_size, void* d_ws, size_t ws_size,
                              hipStream_t stream) {
    (void)in_sizes; (void)n_in; (void)out_size; (void)ws_size;
    const float* x_n1 = (const float*)d_in[0];
    const float* x_n2 = (const float*)d_in[1];
    const int*   e12  = (const int*)d_in[2];
    const int*   e21  = (const int*)d_in[3];
    const int*   pe   = (const int*)d_in[4];
    const float* Win  = (const float*)d_in[5];
    const float* b_in = (const float*)d_in[6];
    const float* Wk   = (const float*)d_in[7];
    const float* bk   = (const float*)d_in[8];
    const float* Wq   = (const float*)d_in[9];
    const float* bq   = (const float*)d_in[10];
    const float* Wv   = (const float*)d_in[11];
    const float* bv   = (const float*)d_in[12];
    const float* Wout = (const float*)d_in[13];
    const float* bout = (const float*)d_in[14];
    float* out = (float*)d_out;

    char* w = (char*)d_ws;
    auto carve = [&](size_t nbytes) -> void* {
        void* p = (void*)w;
        w += (nbytes + 255) & ~(size_t)255;
        return p;
    };
    float* x1    = (float*)carve((size_t)NN * HD * 4);
    float* x2    = (float*)carve((size_t)NN * HD * 4);
    __half* Kh   = (__half*)carve((size_t)2 * NN * HH * 2);
    __half* Qh   = (__half*)carve((size_t)2 * NN * HH * 2);
    __half* Vh   = (__half*)carve((size_t)2 * NN * HH * 2);
    float* ew    = (float*)carve((size_t)2 * 2 * NE * 4);
    float* aggb  = (float*)carve((size_t)2 * NN * HH * 4);
    __half2* Emh2 = (__half2*)carve((size_t)NN * HH * 2);
    __half2* Edh2 = (__half2*)carve((size_t)NN * HH * 2);
    float* sums  = (float*)carve((size_t)2 * 256 * 4);
    int* cnt     = (int*)carve((size_t)2 * NN * 4);
    int* cur12   = (int*)carve((size_t)NN * 4);
    int* cur21   = (int*)carve((size_t)NN * 4);
    int* ptr12   = (int*)carve((size_t)(NN + 1) * 4);
    int* ptr21   = (int*)carve((size_t)(NN + 1) * 4);
    int* rs12    = (int*)carve((size_t)NE * 4);
    int* rs21    = (int*)carve((size_t)NE * 4);
    int* cs12    = (int*)carve((size_t)NE * 4);
    int* cs21    = (int*)carve((size_t)NE * 4);
    int* cnt12 = cnt;
    int* cnt21 = cnt + NN;

    // CSR build
    hipMemsetAsync(cnt, 0, (size_t)2 * NN * 4, stream);
    int eb = (2 * NE + 255) / 256;
    count_kernel<<<eb, 256, 0, stream>>>(e12, e21, cnt12, cnt21);
    scan_kernel<<<2, 1024, 0, stream>>>(cnt12, cnt21, ptr12, ptr21, cur12, cur21);
    fill_kernel<<<eb, 256, 0, stream>>>(e12, e21, cur12, cur21, rs12, rs21, cs12, cs21);

    // input linears + relu
    in_gemm<<<dim3(NN / 16, 1, 2), 256, 0, stream>>>(x_n1, x_n2, Win, b_in, x1, x2);

    for (int l = 0; l < 2; l++) {
        kqv_gemm<<<dim3(NN / 16, 1, 6), 256, 0, stream>>>(
            x1, x2, Wk, Wq, Wv, bk, bq, bv, Kh, Qh, Vh, sums, l);
        conv_fused<<<dim3(NN / 8 * 2), 256, 0, stream>>>(
            ptr12, rs12, cs12, ptr21, rs21, cs21, Kh, Qh, Vh, ew, aggb, sums, l);
        out_gemm<<<dim3(NN / 16, 1, 2), 256, 0, stream>>>(
            aggb, Wout, bout, sums, l, x1, x2, Emh2, Edh2);
    }

    pred_kernel<<<(NP + 255) / 256, 256, 0, stream>>>(
        (const __half*)Emh2, (const __half*)Edh2, pe, out);
}

// Round 13
// 224.701 us; speedup vs baseline: 1.0743x; 1.0743x over previous
//
#include <hip/hip_runtime.h>
#include <hip/hip_fp16.h>

#define NN 10000
#define DIN 128
#define HD 64
#define HH 128          // H*HEADS
#define NE 250000
#define NP 100000

// ---------------- CSR build ----------------

__global__ void count_kernel(const int* e12, const int* e21, int* cnt12, int* cnt21) {
    int t = blockIdx.x * blockDim.x + threadIdx.x;
    if (t < NE)            atomicAdd(&cnt12[e12[NE + t]], 1);
    else if (t < 2 * NE)   atomicAdd(&cnt21[e21[NE + (t - NE)]], 1);
}

__global__ void scan_kernel(const int* cnt12, const int* cnt21,
                            int* ptr12, int* ptr21, int* cur12, int* cur21) {
    const int* cnt = blockIdx.x ? cnt21 : cnt12;
    int* ptr = blockIdx.x ? ptr21 : ptr12;
    int* cur = blockIdx.x ? cur21 : cur12;
    const int T = 1024, C = 10;                 // 1024*10 = 10240 >= 10000
    __shared__ int sm[1024];
    int t = threadIdx.x;
    int v[C]; int tot = 0;
    int base = t * C;
    #pragma unroll
    for (int i = 0; i < C; i++) {
        int id = base + i;
        v[i] = (id < NN) ? cnt[id] : 0;
        tot += v[i];
    }
    sm[t] = tot; __syncthreads();
    for (int off = 1; off < T; off <<= 1) {
        int x = (t >= off) ? sm[t - off] : 0;
        __syncthreads();
        sm[t] += x;
        __syncthreads();
    }
    int run = sm[t] - tot;                      // exclusive prefix
    #pragma unroll
    for (int i = 0; i < C; i++) {
        int id = base + i;
        if (id < NN) { ptr[id] = run; cur[id] = run; }
        run += v[i];
    }
    if (t == T - 1) ptr[NN] = run;
}

// writes rows_sorted AND cols_sorted (dest of each CSR slot)
__global__ void fill_kernel(const int* e12, const int* e21,
                            int* cur12, int* cur21,
                            int* rs12, int* rs21, int* cs12, int* cs21) {
    int t = blockIdx.x * blockDim.x + threadIdx.x;
    if (t < NE) {
        int c = e12[NE + t];
        int p = atomicAdd(&cur12[c], 1);
        rs12[p] = e12[t];
        cs12[p] = c;
    } else if (t < 2 * NE) {
        int e = t - NE;
        int c = e21[NE + e];
        int p = atomicAdd(&cur21[c], 1);
        rs21[p] = e21[e];
        cs21[p] = c;
    }
}

// ---------------- input GEMM (weights staged in LDS) ----------------

__global__ void in_gemm(const float* __restrict__ xn1, const float* __restrict__ xn2,
                        const float* __restrict__ Win, const float* __restrict__ b_in,
                        float* x1, float* x2) {
    int z = blockIdx.z;
    const float4* A4 = (const float4*)(z ? xn2 : xn1);
    const float4* W4 = (const float4*)(Win + (size_t)z * DIN * HD);
    const float4* b4 = (const float4*)(b_in + (size_t)z * HD);
    float4* O4 = (float4*)(z ? x2 : x1);
    __shared__ float As[16 * DIN];              // 8 KB
    __shared__ float Ws[DIN * HD];              // 32 KB
    int tid = threadIdx.x;
    int row0 = blockIdx.x * 16;
    float4* As4 = (float4*)As;
    float4* Ws4 = (float4*)Ws;
    As4[tid]       = A4[(size_t)row0 * 32 + tid];
    As4[tid + 256] = A4[(size_t)row0 * 32 + tid + 256];
    #pragma unroll
    for (int i = 0; i < 8; i++) Ws4[tid + 256 * i] = W4[tid + 256 * i];
    __syncthreads();
    int r = tid >> 4, cg = tid & 15;
    float4 acc = b4[cg];
    const float* a = &As[r * DIN];
    for (int k = 0; k < DIN; k++) {
        float av = a[k];
        float4 w = Ws4[k * 16 + cg];
        acc.x += av * w.x; acc.y += av * w.y; acc.z += av * w.z; acc.w += av * w.w;
    }
    acc.x = fmaxf(acc.x, 0.f); acc.y = fmaxf(acc.y, 0.f);
    acc.z = fmaxf(acc.z, 0.f); acc.w = fmaxf(acc.w, 0.f);
    O4[(size_t)(row0 + r) * 16 + cg] = acc;
}

// ---------------- K/Q/V GEMM (weights staged in LDS) ----------------
// z in [0,6): rel = z/3, kind = z%3 (0=K 1=Q 2=V); outputs fp16 [rel][NN][128].
// block z==0,x==0 zeroes this layer's sum partials.
__global__ void kqv_gemm(const float* __restrict__ x1, const float* __restrict__ x2,
                         const float* __restrict__ Wk, const float* __restrict__ Wq,
                         const float* __restrict__ Wv,
                         const float* __restrict__ bk, const float* __restrict__ bq,
                         const float* __restrict__ bv,
                         __half* Kh, __half* Qh, __half* Vh, float* sums, int l) {
    int z = blockIdx.z;
    int rel = z / 3, kind = z - rel * 3;
    if (z == 0 && blockIdx.x == 0) sums[l * 256 + threadIdx.x] = 0.f;
    const float* xsrc = rel ? x2 : x1;
    const float* xdst = rel ? x1 : x2;
    const float* A = (kind == 1) ? xdst : xsrc;
    size_t wo = (size_t)(l * 2 + rel) * HD * HH;
    size_t bo = (size_t)(l * 2 + rel) * HH;
    const float4* W4 = (const float4*)((kind == 0 ? Wk : kind == 1 ? Wq : Wv) + wo);
    const float4* b4 = (const float4*)((kind == 0 ? bk : kind == 1 ? bq : bv) + bo);
    const float4* A4 = (const float4*)A;
    __shared__ float As[16 * HD];               // 4 KB
    __shared__ float Ws[HD * HH];               // 32 KB
    int tid = threadIdx.x;
    int row0 = blockIdx.x * 16;
    float4* As4 = (float4*)As;
    float4* Ws4 = (float4*)Ws;
    As4[tid] = A4[(size_t)row0 * 16 + tid];     // 16 rows x 16 float4
    #pragma unroll
    for (int i = 0; i < 8; i++) Ws4[tid + 256 * i] = W4[tid + 256 * i];
    __syncthreads();
    int cg = tid & 31, rg = tid >> 5;           // rg 0..7, rows rg*2, rg*2+1
    float4 acc0 = b4[cg], acc1 = acc0;
    const float* a0 = &As[(rg * 2) * HD];
    const float* a1 = &As[(rg * 2 + 1) * HD];
    for (int k = 0; k < HD; k++) {
        float4 w = Ws4[k * 32 + cg];
        float v0 = a0[k], v1 = a1[k];
        acc0.x += v0 * w.x; acc0.y += v0 * w.y; acc0.z += v0 * w.z; acc0.w += v0 * w.w;
        acc1.x += v1 * w.x; acc1.y += v1 * w.y; acc1.z += v1 * w.z; acc1.w += v1 * w.w;
    }
    __half* dst = (kind == 0) ? Kh : (kind == 1) ? Qh : Vh;
    int node = row0 + rg * 2;
    {
        __half2* H2 = (__half2*)(dst + (size_t)rel * NN * HH + (size_t)node * HH + cg * 4);
        float2 lo = {acc0.x, acc0.y}, hi = {acc0.z, acc0.w};
        H2[0] = __float22half2_rn(lo);
        H2[1] = __float22half2_rn(hi);
    }
    {
        __half2* H2 = (__half2*)(dst + (size_t)rel * NN * HH + (size_t)(node + 1) * HH + cg * 4);
        float2 lo = {acc1.x, acc1.y}, hi = {acc1.z, acc1.w};
        H2[0] = __float22half2_rn(lo);
        H2[1] = __float22half2_rn(hi);
    }
}

// ---------------- helpers ----------------

__device__ __forceinline__ float dotc(const uint4& k, const uint4& q) {
    const __half2* kh = (const __half2*)&k;
    const __half2* qh = (const __half2*)&q;
    float s = 0.f;
    #pragma unroll
    for (int i = 0; i < 4; i++) {
        float2 a = __half22float2(kh[i]);
        float2 b = __half22float2(qh[i]);
        s += a.x * b.x + a.y * b.y;
    }
    return s;
}
__device__ __forceinline__ void acc8(const uint4& v, float e, float* acc) {
    const __half2* h = (const __half2*)&v;
    float2 f0 = __half22float2(h[0]), f1 = __half22float2(h[1]);
    float2 f2 = __half22float2(h[2]), f3 = __half22float2(h[3]);
    acc[0] += e*f0.x; acc[1] += e*f0.y; acc[2] += e*f1.x; acc[3] += e*f1.y;
    acc[4] += e*f2.x; acc[5] += e*f2.y; acc[6] += e*f3.x; acc[7] += e*f3.y;
}

// ---------------- fused attention: block = (rel, 8 dest nodes) ----------------
// phase A: 8-LANE GROUP PER EDGE — each group streams one full 128B line per
//          load instruction (8 lines/instr/wave, all bytes used); chunks s =
//          head0 partial, s+8 = head1 partial; 3-step shfl reduce; ew written
//          coalesced from the 8 writer lanes of each wave.
// phase B: wave-per-node weighted-V gather (16-lane groups), reads ew hot.
__global__ __launch_bounds__(256) void conv_fused(
        const int* __restrict__ ptr12, const int* __restrict__ rs12,
        const int* __restrict__ cs12,
        const int* __restrict__ ptr21, const int* __restrict__ rs21,
        const int* __restrict__ cs21,
        const __half* __restrict__ Kh, const __half* __restrict__ Qh,
        const __half* __restrict__ Vh,
        float* __restrict__ ew, float* __restrict__ aggb,
        float* __restrict__ sums, int l) {
    int b = blockIdx.x;
    int rel = b & 1, seg = b >> 1;              // seg in [0, 1250)
    const int* __restrict__ ptr = rel ? ptr21 : ptr12;
    const int* __restrict__ rs  = rel ? rs21 : rs12;
    const int* __restrict__ cs  = rel ? cs21 : cs12;
    const uint4* K = (const uint4*)(Kh + (size_t)rel * NN * HH);
    const uint4* Q = (const uint4*)(Qh + (size_t)rel * NN * HH);
    const uint4* V = (const uint4*)(Vh + (size_t)rel * NN * HH);
    float* __restrict__ ew0 = ew + (size_t)rel * 2 * NE;
    float* __restrict__ ew1 = ew0 + NE;
    float4* A4 = (float4*)(aggb + (size_t)rel * NN * HH);
    int tid = threadIdx.x;
    int c0 = seg * 8;
    int jb0 = ptr[c0], je0 = ptr[c0 + 8];

    // ---- phase A: 32 groups x 8 lanes ----
    int s8 = tid & 7;
    float s0 = 0.f, s1 = 0.f;
    for (int j = jb0 + (tid >> 3); j < je0; j += 32) {
        int row = rs[j], col = cs[j];
        uint4 k0 = K[(size_t)row * 16 + s8];
        uint4 k1 = K[(size_t)row * 16 + 8 + s8];
        uint4 q0 = Q[(size_t)col * 16 + s8];
        uint4 q1 = Q[(size_t)col * 16 + 8 + s8];
        float p0 = dotc(k0, q0);
        float p1 = dotc(k1, q1);
        #pragma unroll
        for (int off = 1; off <= 4; off <<= 1) {
            p0 += __shfl_xor(p0, off);
            p1 += __shfl_xor(p1, off);
        }
        p0 *= 0.125f; p1 *= 0.125f;
        p0 = p0 > 0.f ? p0 : 0.2f * p0;
        p1 = p1 > 0.f ? p1 : 0.2f * p1;
        float e0 = __expf(p0), e1 = __expf(p1);
        if (s8 == 0) {
            ew0[j] = e0; ew1[j] = e1;
            s0 += e0; s1 += e1;
        }
    }
    // combine the 8 writer lanes of each wave (others hold 0)
    #pragma unroll
    for (int off = 8; off <= 32; off <<= 1) {
        s0 += __shfl_xor(s0, off);
        s1 += __shfl_xor(s1, off);
    }
    __shared__ float sred[4][2];
    int wave = tid >> 6, lane = tid & 63;
    if (lane == 0) { sred[wave][0] = s0; sred[wave][1] = s1; }
    __syncthreads();                            // also publishes ew to the block
    if (tid < 2) {
        float t = sred[0][tid] + sred[1][tid] + sred[2][tid] + sred[3][tid];
        atomicAdd(&sums[l * 256 + rel * 128 + tid * 64 + (seg & 63)], t);
    }

    // ---- phase B: 4 waves x 2 nodes each ----
    int g = lane >> 4, sl = lane & 15;
    const float* __restrict__ wp = ew0 + (size_t)(sl >> 3) * NE;   // head plane
    #pragma unroll
    for (int ni = 0; ni < 2; ni++) {
        int c = c0 + wave * 2 + ni;
        float acc[8] = {0,0,0,0,0,0,0,0};
        int jb = ptr[c], je = ptr[c + 1];
        int o = jb + g;
        int r0 = (o      < je) ? rs[o]      : -1;
        int r1 = (o + 4  < je) ? rs[o + 4]  : -1;
        int r2 = (o + 8  < je) ? rs[o + 8]  : -1;
        int r3 = (o + 12 < je) ? rs[o + 12] : -1;
        for (int j = o; j < je; j += 16) {
            int n0 = (j + 16 < je) ? rs[j + 16] : -1;
            int n1 = (j + 20 < je) ? rs[j + 20] : -1;
            int n2 = (j + 24 < je) ? rs[j + 24] : -1;
            int n3 = (j + 28 < je) ? rs[j + 28] : -1;
            float w0 = (r0 >= 0) ? wp[j]      : 0.f;
            float w1 = (r1 >= 0) ? wp[j + 4]  : 0.f;
            float w2 = (r2 >= 0) ? wp[j + 8]  : 0.f;
            float w3 = (r3 >= 0) ? wp[j + 12] : 0.f;
            uint4 v0 = V[(size_t)(r0 >= 0 ? r0 : 0) * 16 + sl];
            uint4 v1 = V[(size_t)(r1 >= 0 ? r1 : 0) * 16 + sl];
            uint4 v2 = V[(size_t)(r2 >= 0 ? r2 : 0) * 16 + sl];
            uint4 v3 = V[(size_t)(r3 >= 0 ? r3 : 0) * 16 + sl];
            acc8(v0, w0, acc); acc8(v1, w1, acc);
            acc8(v2, w2, acc); acc8(v3, w3, acc);
            r0 = n0; r1 = n1; r2 = n2; r3 = n3;
        }
        #pragma unroll
        for (int i = 0; i < 8; i++) {
            acc[i] += __shfl_xor(acc[i], 16);
            acc[i] += __shfl_xor(acc[i], 32);
        }
        if (g == 0) {
            float4 t0 = {acc[0], acc[1], acc[2], acc[3]};
            float4 t1 = {acc[4], acc[5], acc[6], acc[7]};
            A4[(size_t)c * 32 + 2 * sl]     = t0;
            A4[(size_t)c * 32 + 2 * sl + 1] = t1;
        }
    }
}

// ---------------- out GEMM (softmax scale folded; W staged in LDS) ----------
__global__ void out_gemm(const float* __restrict__ aggb,
                         const float* __restrict__ Wout, const float* __restrict__ bout,
                         const float* __restrict__ sums, int l,
                         float* x1, float* x2, __half2* Emh2, __half2* Edh2) {
    int z = blockIdx.z;
    int sel = z ? 0 : 1;                        // which relation's aggregate
    const float4* A4 = (const float4*)(aggb + (size_t)sel * NN * HH);
    const float4* W4 = (const float4*)(Wout + (size_t)(l * 2 + z) * HH * HD);
    const float4* b4 = (const float4*)(bout + (size_t)(l * 2 + z) * HD);
    float4* X4 = (float4*)(z ? x2 : x1);
    __half2* E2 = z ? Edh2 : Emh2;
    __shared__ float As[16 * HH];               // 8 KB
    __shared__ float Ws[HH * HD];               // 32 KB
    __shared__ float invs[2];
    int tid = threadIdx.x;
    if (tid < 128) {
        int h = tid >> 6;
        float v = sums[l * 256 + sel * 128 + h * 64 + (tid & 63)];
        #pragma unroll
        for (int off = 1; off <= 32; off <<= 1) v += __shfl_xor(v, off);
        if ((tid & 63) == 0) invs[h] = 1.f / v;
    }
    __syncthreads();
    float inv0 = invs[0], inv1 = invs[1];
    int row0 = blockIdx.x * 16;
    float4* As4 = (float4*)As;
    float4* Ws4 = (float4*)Ws;
    {
        float4 t0 = A4[(size_t)row0 * 32 + tid];
        float4 t1 = A4[(size_t)row0 * 32 + tid + 256];
        float s0 = ((tid & 31) < 16) ? inv0 : inv1;   // cols 0-63 = head0
        t0.x *= s0; t0.y *= s0; t0.z *= s0; t0.w *= s0;
        t1.x *= s0; t1.y *= s0; t1.z *= s0; t1.w *= s0;
        As4[tid] = t0; As4[tid + 256] = t1;
    }
    #pragma unroll
    for (int i = 0; i < 8; i++) Ws4[tid + 256 * i] = W4[tid + 256 * i];
    __syncthreads();
    int r = tid >> 4, cg = tid & 15;
    float4 acc = b4[cg];
    const float* a = &As[r * HH];
    for (int k = 0; k < HH; k++) {
        float av = a[k];
        float4 w = Ws4[k * 16 + cg];
        acc.x += av * w.x; acc.y += av * w.y; acc.z += av * w.z; acc.w += av * w.w;
    }
    int node = row0 + r;
    X4[(size_t)node * 16 + cg] = acc;
    float2 lo = {acc.x, acc.y}, hi = {acc.z, acc.w};
    E2[(size_t)node * 64 + l * 32 + cg * 2]     = __float22half2_rn(lo);
    E2[(size_t)node * 64 + l * 32 + cg * 2 + 1] = __float22half2_rn(hi);
}

// ---------------- prediction (8-lane group per pair) ----------------
__global__ __launch_bounds__(256) void pred_kernel(
        const __half* __restrict__ Emh, const __half* __restrict__ Edh,
        const int* __restrict__ pe, float* out) {
    int grp = (blockIdx.x * 256 + threadIdx.x) >> 3;   // pair index
    int s8 = threadIdx.x & 7;
    if (grp >= NP) return;
    int m = pe[grp], d = pe[NP + grp];
    const uint4* a = (const uint4*)Emh + (size_t)m * 16;
    const uint4* b = (const uint4*)Edh + (size_t)d * 16;
    float acc = dotc(a[s8], b[s8]) + dotc(a[8 + s8], b[8 + s8]);
    #pragma unroll
    for (int off = 1; off <= 4; off <<= 1) acc += __shfl_xor(acc, off);
    if (s8 == 0) out[grp] = acc;
}

// ---------------- host ----------------

extern "C" void kernel_launch(void* const* d_in, const int* in_sizes, int n_in,
                              void* d_out, int out_size, void* d_ws, size_t ws_size,
                              hipStream_t stream) {
    (void)in_sizes; (void)n_in; (void)out_size; (void)ws_size;
    const float* x_n1 = (const float*)d_in[0];
    const float* x_n2 = (const float*)d_in[1];
    const int*   e12  = (const int*)d_in[2];
    const int*   e21  = (const int*)d_in[3];
    const int*   pe   = (const int*)d_in[4];
    const float* Win  = (const float*)d_in[5];
    const float* b_in = (const float*)d_in[6];
    const float* Wk   = (const float*)d_in[7];
    const float* bk   = (const float*)d_in[8];
    const float* Wq   = (const float*)d_in[9];
    const float* bq   = (const float*)d_in[10];
    const float* Wv   = (const float*)d_in[11];
    const float* bv   = (const float*)d_in[12];
    const float* Wout = (const float*)d_in[13];
    const float* bout = (const float*)d_in[14];
    float* out = (float*)d_out;

    char* w = (char*)d_ws;
    auto carve = [&](size_t nbytes) -> void* {
        void* p = (void*)w;
        w += (nbytes + 255) & ~(size_t)255;
        return p;
    };
    float* x1    = (float*)carve((size_t)NN * HD * 4);
    float* x2    = (float*)carve((size_t)NN * HD * 4);
    __half* Kh   = (__half*)carve((size_t)2 * NN * HH * 2);
    __half* Qh   = (__half*)carve((size_t)2 * NN * HH * 2);
    __half* Vh   = (__half*)carve((size_t)2 * NN * HH * 2);
    float* ew    = (float*)carve((size_t)2 * 2 * NE * 4);
    float* aggb  = (float*)carve((size_t)2 * NN * HH * 4);
    __half2* Emh2 = (__half2*)carve((size_t)NN * HH * 2);
    __half2* Edh2 = (__half2*)carve((size_t)NN * HH * 2);
    float* sums  = (float*)carve((size_t)2 * 256 * 4);
    int* cnt     = (int*)carve((size_t)2 * NN * 4);
    int* cur12   = (int*)carve((size_t)NN * 4);
    int* cur21   = (int*)carve((size_t)NN * 4);
    int* ptr12   = (int*)carve((size_t)(NN + 1) * 4);
    int* ptr21   = (int*)carve((size_t)(NN + 1) * 4);
    int* rs12    = (int*)carve((size_t)NE * 4);
    int* rs21    = (int*)carve((size_t)NE * 4);
    int* cs12    = (int*)carve((size_t)NE * 4);
    int* cs21    = (int*)carve((size_t)NE * 4);
    int* cnt12 = cnt;
    int* cnt21 = cnt + NN;

    // CSR build
    hipMemsetAsync(cnt, 0, (size_t)2 * NN * 4, stream);
    int eb = (2 * NE + 255) / 256;
    count_kernel<<<eb, 256, 0, stream>>>(e12, e21, cnt12, cnt21);
    scan_kernel<<<2, 1024, 0, stream>>>(cnt12, cnt21, ptr12, ptr21, cur12, cur21);
    fill_kernel<<<eb, 256, 0, stream>>>(e12, e21, cur12, cur21, rs12, rs21, cs12, cs21);

    // input linears + relu
    in_gemm<<<dim3(NN / 16, 1, 2), 256, 0, stream>>>(x_n1, x_n2, Win, b_in, x1, x2);

    for (int l = 0; l < 2; l++) {
        kqv_gemm<<<dim3(NN / 16, 1, 6), 256, 0, stream>>>(
            x1, x2, Wk, Wq, Wv, bk, bq, bv, Kh, Qh, Vh, sums, l);
        conv_fused<<<dim3(NN / 8 * 2), 256, 0, stream>>>(
            ptr12, rs12, cs12, ptr21, rs21, cs21, Kh, Qh, Vh, ew, aggb, sums, l);
        out_gemm<<<dim3(NN / 16, 1, 2), 256, 0, stream>>>(
            aggb, Wout, bout, sums, l, x1, x2, Emh2, Edh2);
    }

    pred_kernel<<<(NP * 8 + 255) / 256, 256, 0, stream>>>(
        (const __half*)Emh2, (const __half*)Edh2, pe, out);
}

// Round 14
// 221.981 us; speedup vs baseline: 1.0874x; 1.0123x over previous
//
#include <hip/hip_runtime.h>
#include <hip/hip_fp16.h>

#define NN 10000
#define DIN 128
#define HD 64
#define HH 128          // H*HEADS
#define NE 250000
#define NP 100000

// ---------------- CSR build ----------------

__global__ void count_kernel(const int* e12, const int* e21, int* cnt12, int* cnt21) {
    int t = blockIdx.x * blockDim.x + threadIdx.x;
    if (t < NE)            atomicAdd(&cnt12[e12[NE + t]], 1);
    else if (t < 2 * NE)   atomicAdd(&cnt21[e21[NE + (t - NE)]], 1);
}

__global__ void scan_kernel(const int* cnt12, const int* cnt21,
                            int* ptr12, int* ptr21, int* cur12, int* cur21) {
    const int* cnt = blockIdx.x ? cnt21 : cnt12;
    int* ptr = blockIdx.x ? ptr21 : ptr12;
    int* cur = blockIdx.x ? cur21 : cur12;
    const int T = 1024, C = 10;                 // 1024*10 = 10240 >= 10000
    __shared__ int sm[1024];
    int t = threadIdx.x;
    int v[C]; int tot = 0;
    int base = t * C;
    #pragma unroll
    for (int i = 0; i < C; i++) {
        int id = base + i;
        v[i] = (id < NN) ? cnt[id] : 0;
        tot += v[i];
    }
    sm[t] = tot; __syncthreads();
    for (int off = 1; off < T; off <<= 1) {
        int x = (t >= off) ? sm[t - off] : 0;
        __syncthreads();
        sm[t] += x;
        __syncthreads();
    }
    int run = sm[t] - tot;                      // exclusive prefix
    #pragma unroll
    for (int i = 0; i < C; i++) {
        int id = base + i;
        if (id < NN) { ptr[id] = run; cur[id] = run; }
        run += v[i];
    }
    if (t == T - 1) ptr[NN] = run;
}

// writes packed (row, col) per CSR slot
__global__ void fill_kernel(const int* e12, const int* e21,
                            int* cur12, int* cur21, int2* rc12, int2* rc21) {
    int t = blockIdx.x * blockDim.x + threadIdx.x;
    if (t < NE) {
        int c = e12[NE + t];
        int p = atomicAdd(&cur12[c], 1);
        rc12[p] = make_int2(e12[t], c);
    } else if (t < 2 * NE) {
        int e = t - NE;
        int c = e21[NE + e];
        int p = atomicAdd(&cur21[c], 1);
        rc21[p] = make_int2(e21[e], c);
    }
}

// ---------------- shared device pieces ----------------

__device__ __forceinline__ float dotc(const uint4& k, const uint4& q) {
    const __half2* kh = (const __half2*)&k;
    const __half2* qh = (const __half2*)&q;
    float s = 0.f;
    #pragma unroll
    for (int i = 0; i < 4; i++) {
        float2 a = __half22float2(kh[i]);
        float2 b = __half22float2(qh[i]);
        s += a.x * b.x + a.y * b.y;
    }
    return s;
}
__device__ __forceinline__ void acc8(const uint4& v, float e, float* acc) {
    const __half2* h = (const __half2*)&v;
    float2 f0 = __half22float2(h[0]), f1 = __half22float2(h[1]);
    float2 f2 = __half22float2(h[2]), f3 = __half22float2(h[3]);
    acc[0] += e*f0.x; acc[1] += e*f0.y; acc[2] += e*f1.x; acc[3] += e*f1.y;
    acc[4] += e*f2.x; acc[5] += e*f2.y; acc[6] += e*f3.x; acc[7] += e*f3.y;
}

// 3 K/Q/V GEMM phases over the block's 16 x-rows held in LDS (Xs, 16x64 f32).
// node type z: K,V -> rel=z ; Q -> rel=1-z. W staged in Ws (32 KB) per phase.
__device__ __forceinline__ void kqv_phases(
        int z, int l, const float* Xs, float4* Ws4, int row0, int tid,
        const float* __restrict__ Wk, const float* __restrict__ Wq,
        const float* __restrict__ Wv,
        const float* __restrict__ bk, const float* __restrict__ bq,
        const float* __restrict__ bv,
        __half* Kh, __half* Qh, __half* Vh) {
    #pragma unroll
    for (int kind = 0; kind < 3; kind++) {
        int rel = (kind == 1) ? (1 - z) : z;
        size_t wo = (size_t)(l * 2 + rel) * HD * HH;
        size_t bo = (size_t)(l * 2 + rel) * HH;
        const float4* W4 = (const float4*)((kind == 0 ? Wk : kind == 1 ? Wq : Wv) + wo);
        const float4* b4 = (const float4*)((kind == 0 ? bk : kind == 1 ? bq : bv) + bo);
        #pragma unroll
        for (int i = 0; i < 8; i++) Ws4[tid + 256 * i] = W4[tid + 256 * i];
        __syncthreads();
        int cg = tid & 31, rg = tid >> 5;       // rg 0..7, rows rg*2, rg*2+1
        float4 acc0 = b4[cg], acc1 = acc0;
        const float* a0 = &Xs[(rg * 2) * HD];
        const float* a1 = &Xs[(rg * 2 + 1) * HD];
        for (int k = 0; k < HD; k++) {
            float4 w = Ws4[k * 32 + cg];
            float v0 = a0[k], v1 = a1[k];
            acc0.x += v0 * w.x; acc0.y += v0 * w.y; acc0.z += v0 * w.z; acc0.w += v0 * w.w;
            acc1.x += v1 * w.x; acc1.y += v1 * w.y; acc1.z += v1 * w.z; acc1.w += v1 * w.w;
        }
        __half* dst = (kind == 0) ? Kh : (kind == 1) ? Qh : Vh;
        int node = row0 + rg * 2;
        {
            __half2* H2 = (__half2*)(dst + (size_t)rel * NN * HH + (size_t)node * HH + cg * 4);
            float2 lo = {acc0.x, acc0.y}, hi = {acc0.z, acc0.w};
            H2[0] = __float22half2_rn(lo);
            H2[1] = __float22half2_rn(hi);
        }
        {
            __half2* H2 = (__half2*)(dst + (size_t)rel * NN * HH + (size_t)(node + 1) * HH + cg * 4);
            float2 lo = {acc1.x, acc1.y}, hi = {acc1.z, acc1.w};
            H2[0] = __float22half2_rn(lo);
            H2[1] = __float22half2_rn(hi);
        }
        __syncthreads();                        // Ws reads done before next staging
    }
}

// ---------------- fused: input GEMM + layer-0 K/Q/V ----------------
// z = node type (0 -> x1 rows, 1 -> x2 rows); x kept in LDS only.
__global__ __launch_bounds__(256) void in_kqv(
        const float* __restrict__ xn1, const float* __restrict__ xn2,
        const float* __restrict__ Win, const float* __restrict__ b_in,
        const float* __restrict__ Wk, const float* __restrict__ Wq,
        const float* __restrict__ Wv,
        const float* __restrict__ bk, const float* __restrict__ bq,
        const float* __restrict__ bv,
        __half* Kh, __half* Qh, __half* Vh) {
    int z = blockIdx.z;
    int tid = threadIdx.x;
    int row0 = blockIdx.x * 16;
    __shared__ float As[16 * DIN];              // 8 KB
    __shared__ float Ws[DIN * HD];              // 32 KB
    __shared__ float Xs[16 * HD];               // 4 KB
    float4* As4 = (float4*)As;
    float4* Ws4 = (float4*)Ws;
    float4* Xs4 = (float4*)Xs;
    {
        const float4* A4 = (const float4*)(z ? xn2 : xn1);
        const float4* W4 = (const float4*)(Win + (size_t)z * DIN * HD);
        const float4* b4 = (const float4*)(b_in + (size_t)z * HD);
        As4[tid]       = A4[(size_t)row0 * 32 + tid];
        As4[tid + 256] = A4[(size_t)row0 * 32 + tid + 256];
        #pragma unroll
        for (int i = 0; i < 8; i++) Ws4[tid + 256 * i] = W4[tid + 256 * i];
        __syncthreads();
        int r = tid >> 4, cg = tid & 15;
        float4 acc = b4[cg];
        const float* a = &As[r * DIN];
        for (int k = 0; k < DIN; k++) {
            float av = a[k];
            float4 w = Ws4[k * 16 + cg];
            acc.x += av * w.x; acc.y += av * w.y; acc.z += av * w.z; acc.w += av * w.w;
        }
        acc.x = fmaxf(acc.x, 0.f); acc.y = fmaxf(acc.y, 0.f);
        acc.z = fmaxf(acc.z, 0.f); acc.w = fmaxf(acc.w, 0.f);
        Xs4[r * 16 + cg] = acc;
        __syncthreads();
    }
    kqv_phases(z, 0, Xs, Ws4, row0, tid, Wk, Wq, Wv, bk, bq, bv, Kh, Qh, Vh);
}

// ---------------- fused: out GEMM (layer l) + K/Q/V (layer l+1) ----------------
__global__ __launch_bounds__(256) void out_kqv(
        const float* __restrict__ aggb,
        const float* __restrict__ Wout, const float* __restrict__ bout,
        const float* __restrict__ sums, int l,
        const float* __restrict__ Wk, const float* __restrict__ Wq,
        const float* __restrict__ Wv,
        const float* __restrict__ bk, const float* __restrict__ bq,
        const float* __restrict__ bv,
        __half* Kh, __half* Qh, __half* Vh,
        __half2* Emh2, __half2* Edh2) {
    int z = blockIdx.z;
    int sel = z ? 0 : 1;                        // which relation's aggregate
    int tid = threadIdx.x;
    int row0 = blockIdx.x * 16;
    __shared__ float As[16 * HH];               // 8 KB
    __shared__ float Ws[HH * HD];               // 32 KB
    __shared__ float Xs[16 * HD];               // 4 KB
    __shared__ float invs[2];
    float4* As4 = (float4*)As;
    float4* Ws4 = (float4*)Ws;
    float4* Xs4 = (float4*)Xs;
    {
        const float4* A4 = (const float4*)(aggb + (size_t)sel * NN * HH);
        const float4* W4 = (const float4*)(Wout + (size_t)(l * 2 + z) * HH * HD);
        const float4* b4 = (const float4*)(bout + (size_t)(l * 2 + z) * HD);
        __half2* E2 = z ? Edh2 : Emh2;
        if (tid < 128) {
            int h = tid >> 6;
            float v = sums[l * 256 + sel * 128 + h * 64 + (tid & 63)];
            #pragma unroll
            for (int off = 1; off <= 32; off <<= 1) v += __shfl_xor(v, off);
            if ((tid & 63) == 0) invs[h] = 1.f / v;
        }
        __syncthreads();
        float inv0 = invs[0], inv1 = invs[1];
        {
            float4 t0 = A4[(size_t)row0 * 32 + tid];
            float4 t1 = A4[(size_t)row0 * 32 + tid + 256];
            float s0 = ((tid & 31) < 16) ? inv0 : inv1;   // cols 0-63 = head0
            t0.x *= s0; t0.y *= s0; t0.z *= s0; t0.w *= s0;
            t1.x *= s0; t1.y *= s0; t1.z *= s0; t1.w *= s0;
            As4[tid] = t0; As4[tid + 256] = t1;
        }
        #pragma unroll
        for (int i = 0; i < 8; i++) Ws4[tid + 256 * i] = W4[tid + 256 * i];
        __syncthreads();
        int r = tid >> 4, cg = tid & 15;
        float4 acc = b4[cg];
        const float* a = &As[r * HH];
        for (int k = 0; k < HH; k++) {
            float av = a[k];
            float4 w = Ws4[k * 16 + cg];
            acc.x += av * w.x; acc.y += av * w.y; acc.z += av * w.z; acc.w += av * w.w;
        }
        int node = row0 + r;
        Xs4[r * 16 + cg] = acc;
        float2 lo = {acc.x, acc.y}, hi = {acc.z, acc.w};
        E2[(size_t)node * 64 + l * 32 + cg * 2]     = __float22half2_rn(lo);
        E2[(size_t)node * 64 + l * 32 + cg * 2 + 1] = __float22half2_rn(hi);
        __syncthreads();
    }
    kqv_phases(z, l + 1, Xs, Ws4, row0, tid, Wk, Wq, Wv, bk, bq, bv, Kh, Qh, Vh);
}

// ---------------- final out GEMM (layer 1; Em/Ed only) ----------------
__global__ __launch_bounds__(256) void out_last(
        const float* __restrict__ aggb,
        const float* __restrict__ Wout, const float* __restrict__ bout,
        const float* __restrict__ sums, int l,
        __half2* Emh2, __half2* Edh2) {
    int z = blockIdx.z;
    int sel = z ? 0 : 1;
    const float4* A4 = (const float4*)(aggb + (size_t)sel * NN * HH);
    const float4* W4 = (const float4*)(Wout + (size_t)(l * 2 + z) * HH * HD);
    const float4* b4 = (const float4*)(bout + (size_t)(l * 2 + z) * HD);
    __half2* E2 = z ? Edh2 : Emh2;
    __shared__ float As[16 * HH];
    __shared__ float Ws[HH * HD];
    __shared__ float invs[2];
    int tid = threadIdx.x;
    if (tid < 128) {
        int h = tid >> 6;
        float v = sums[l * 256 + sel * 128 + h * 64 + (tid & 63)];
        #pragma unroll
        for (int off = 1; off <= 32; off <<= 1) v += __shfl_xor(v, off);
        if ((tid & 63) == 0) invs[h] = 1.f / v;
    }
    __syncthreads();
    float inv0 = invs[0], inv1 = invs[1];
    int row0 = blockIdx.x * 16;
    float4* As4 = (float4*)As;
    float4* Ws4 = (float4*)Ws;
    {
        float4 t0 = A4[(size_t)row0 * 32 + tid];
        float4 t1 = A4[(size_t)row0 * 32 + tid + 256];
        float s0 = ((tid & 31) < 16) ? inv0 : inv1;
        t0.x *= s0; t0.y *= s0; t0.z *= s0; t0.w *= s0;
        t1.x *= s0; t1.y *= s0; t1.z *= s0; t1.w *= s0;
        As4[tid] = t0; As4[tid + 256] = t1;
    }
    #pragma unroll
    for (int i = 0; i < 8; i++) Ws4[tid + 256 * i] = W4[tid + 256 * i];
    __syncthreads();
    int r = tid >> 4, cg = tid & 15;
    float4 acc = b4[cg];
    const float* a = &As[r * HH];
    for (int k = 0; k < HH; k++) {
        float av = a[k];
        float4 w = Ws4[k * 16 + cg];
        acc.x += av * w.x; acc.y += av * w.y; acc.z += av * w.z; acc.w += av * w.w;
    }
    int node = row0 + r;
    float2 lo = {acc.x, acc.y}, hi = {acc.z, acc.w};
    E2[(size_t)node * 64 + l * 32 + cg * 2]     = __float22half2_rn(lo);
    E2[(size_t)node * 64 + l * 32 + cg * 2 + 1] = __float22half2_rn(hi);
}

// ---------------- fused attention: block = (rel, 8 dest nodes) ----------------
__global__ __launch_bounds__(256) void conv_fused(
        const int* __restrict__ ptr12, const int2* __restrict__ rc12,
        const int* __restrict__ ptr21, const int2* __restrict__ rc21,
        const __half* __restrict__ Kh, const __half* __restrict__ Qh,
        const __half* __restrict__ Vh,
        float* __restrict__ ew, float* __restrict__ aggb,
        float* __restrict__ sums, int l) {
    int b = blockIdx.x;
    int rel = b & 1, seg = b >> 1;              // seg in [0, 1250)
    const int* __restrict__ ptr = rel ? ptr21 : ptr12;
    const int2* __restrict__ rc = rel ? rc21 : rc12;
    const uint4* K = (const uint4*)(Kh + (size_t)rel * NN * HH);
    const uint4* Q = (const uint4*)(Qh + (size_t)rel * NN * HH);
    const uint4* V = (const uint4*)(Vh + (size_t)rel * NN * HH);
    float* __restrict__ ew0 = ew + (size_t)rel * 2 * NE;
    float* __restrict__ ew1 = ew0 + NE;
    float4* A4 = (float4*)(aggb + (size_t)rel * NN * HH);
    int tid = threadIdx.x;
    int c0 = seg * 8;
    int jb0 = ptr[c0], je0 = ptr[c0 + 8];

    // ---- phase A: 8-lane group per edge ----
    int s8 = tid & 7;
    float s0 = 0.f, s1 = 0.f;
    for (int j = jb0 + (tid >> 3); j < je0; j += 32) {
        int2 e = rc[j];
        uint4 k0 = K[(size_t)e.x * 16 + s8];
        uint4 k1 = K[(size_t)e.x * 16 + 8 + s8];
        uint4 q0 = Q[(size_t)e.y * 16 + s8];
        uint4 q1 = Q[(size_t)e.y * 16 + 8 + s8];
        float p0 = dotc(k0, q0);
        float p1 = dotc(k1, q1);
        #pragma unroll
        for (int off = 1; off <= 4; off <<= 1) {
            p0 += __shfl_xor(p0, off);
            p1 += __shfl_xor(p1, off);
        }
        p0 *= 0.125f; p1 *= 0.125f;
        p0 = p0 > 0.f ? p0 : 0.2f * p0;
        p1 = p1 > 0.f ? p1 : 0.2f * p1;
        float e0 = __expf(p0), e1 = __expf(p1);
        if (s8 == 0) {
            ew0[j] = e0; ew1[j] = e1;
            s0 += e0; s1 += e1;
        }
    }
    #pragma unroll
    for (int off = 8; off <= 32; off <<= 1) {
        s0 += __shfl_xor(s0, off);
        s1 += __shfl_xor(s1, off);
    }
    __shared__ float sred[4][2];
    int wave = tid >> 6, lane = tid & 63;
    if (lane == 0) { sred[wave][0] = s0; sred[wave][1] = s1; }
    __syncthreads();                            // also publishes ew to the block
    if (tid < 2) {
        float t = sred[0][tid] + sred[1][tid] + sred[2][tid] + sred[3][tid];
        atomicAdd(&sums[l * 256 + rel * 128 + tid * 64 + (seg & 63)], t);
    }

    // ---- phase B: 4 waves x 2 nodes each ----
    int g = lane >> 4, sl = lane & 15;
    const float* __restrict__ wp = ew0 + (size_t)(sl >> 3) * NE;   // head plane
    #pragma unroll
    for (int ni = 0; ni < 2; ni++) {
        int c = c0 + wave * 2 + ni;
        float acc[8] = {0,0,0,0,0,0,0,0};
        int jb = ptr[c], je = ptr[c + 1];
        int o = jb + g;
        int r0 = (o      < je) ? rc[o].x      : -1;
        int r1 = (o + 4  < je) ? rc[o + 4].x  : -1;
        int r2 = (o + 8  < je) ? rc[o + 8].x  : -1;
        int r3 = (o + 12 < je) ? rc[o + 12].x : -1;
        for (int j = o; j < je; j += 16) {
            int n0 = (j + 16 < je) ? rc[j + 16].x : -1;
            int n1 = (j + 20 < je) ? rc[j + 20].x : -1;
            int n2 = (j + 24 < je) ? rc[j + 24].x : -1;
            int n3 = (j + 28 < je) ? rc[j + 28].x : -1;
            float w0 = (r0 >= 0) ? wp[j]      : 0.f;
            float w1 = (r1 >= 0) ? wp[j + 4]  : 0.f;
            float w2 = (r2 >= 0) ? wp[j + 8]  : 0.f;
            float w3 = (r3 >= 0) ? wp[j + 12] : 0.f;
            uint4 v0 = V[(size_t)(r0 >= 0 ? r0 : 0) * 16 + sl];
            uint4 v1 = V[(size_t)(r1 >= 0 ? r1 : 0) * 16 + sl];
            uint4 v2 = V[(size_t)(r2 >= 0 ? r2 : 0) * 16 + sl];
            uint4 v3 = V[(size_t)(r3 >= 0 ? r3 : 0) * 16 + sl];
            acc8(v0, w0, acc); acc8(v1, w1, acc);
            acc8(v2, w2, acc); acc8(v3, w3, acc);
            r0 = n0; r1 = n1; r2 = n2; r3 = n3;
        }
        #pragma unroll
        for (int i = 0; i < 8; i++) {
            acc[i] += __shfl_xor(acc[i], 16);
            acc[i] += __shfl_xor(acc[i], 32);
        }
        if (g == 0) {
            float4 t0 = {acc[0], acc[1], acc[2], acc[3]};
            float4 t1 = {acc[4], acc[5], acc[6], acc[7]};
            A4[(size_t)c * 32 + 2 * sl]     = t0;
            A4[(size_t)c * 32 + 2 * sl + 1] = t1;
        }
    }
}

// ---------------- prediction (8-lane group per pair) ----------------
__global__ __launch_bounds__(256) void pred_kernel(
        const __half* __restrict__ Emh, const __half* __restrict__ Edh,
        const int* __restrict__ pe, float* out) {
    int grp = (blockIdx.x * 256 + threadIdx.x) >> 3;   // pair index
    int s8 = threadIdx.x & 7;
    if (grp >= NP) return;
    int m = pe[grp], d = pe[NP + grp];
    const uint4* a = (const uint4*)Emh + (size_t)m * 16;
    const uint4* b = (const uint4*)Edh + (size_t)d * 16;
    float acc = dotc(a[s8], b[s8]) + dotc(a[8 + s8], b[8 + s8]);
    #pragma unroll
    for (int off = 1; off <= 4; off <<= 1) acc += __shfl_xor(acc, off);
    if (s8 == 0) out[grp] = acc;
}

// ---------------- host ----------------

extern "C" void kernel_launch(void* const* d_in, const int* in_sizes, int n_in,
                              void* d_out, int out_size, void* d_ws, size_t ws_size,
                              hipStream_t stream) {
    (void)in_sizes; (void)n_in; (void)out_size; (void)ws_size;
    const float* x_n1 = (const float*)d_in[0];
    const float* x_n2 = (const float*)d_in[1];
    const int*   e12  = (const int*)d_in[2];
    const int*   e21  = (const int*)d_in[3];
    const int*   pe   = (const int*)d_in[4];
    const float* Win  = (const float*)d_in[5];
    const float* b_in = (const float*)d_in[6];
    const float* Wk   = (const float*)d_in[7];
    const float* bk   = (const float*)d_in[8];
    const float* Wq   = (const float*)d_in[9];
    const float* bq   = (const float*)d_in[10];
    const float* Wv   = (const float*)d_in[11];
    const float* bv   = (const float*)d_in[12];
    const float* Wout = (const float*)d_in[13];
    const float* bout = (const float*)d_in[14];
    float* out = (float*)d_out;

    char* w = (char*)d_ws;
    auto carve = [&](size_t nbytes) -> void* {
        void* p = (void*)w;
        w += (nbytes + 255) & ~(size_t)255;
        return p;
    };
    __half* Kh   = (__half*)carve((size_t)2 * NN * HH * 2);
    __half* Qh   = (__half*)carve((size_t)2 * NN * HH * 2);
    __half* Vh   = (__half*)carve((size_t)2 * NN * HH * 2);
    float* ew    = (float*)carve((size_t)2 * 2 * NE * 4);
    float* aggb  = (float*)carve((size_t)2 * NN * HH * 4);
    __half2* Emh2 = (__half2*)carve((size_t)NN * HH * 2);
    __half2* Edh2 = (__half2*)carve((size_t)NN * HH * 2);
    int* cnt     = (int*)carve((size_t)2 * NN * 4);    // cnt + sums: one memset
    float* sums  = (float*)carve((size_t)2 * 256 * 4);
    int* cur12   = (int*)carve((size_t)NN * 4);
    int* cur21   = (int*)carve((size_t)NN * 4);
    int* ptr12   = (int*)carve((size_t)(NN + 1) * 4);
    int* ptr21   = (int*)carve((size_t)(NN + 1) * 4);
    int2* rc12   = (int2*)carve((size_t)NE * 8);
    int2* rc21   = (int2*)carve((size_t)NE * 8);
    int* cnt12 = cnt;
    int* cnt21 = cnt + NN;

    // zero cnt + sums (adjacent carves) in one memset
    size_t zbytes = (((size_t)2 * NN * 4 + 255) & ~(size_t)255) + (size_t)2 * 256 * 4;
    hipMemsetAsync(cnt, 0, zbytes, stream);

    // CSR build
    int eb = (2 * NE + 255) / 256;
    count_kernel<<<eb, 256, 0, stream>>>(e12, e21, cnt12, cnt21);
    scan_kernel<<<2, 1024, 0, stream>>>(cnt12, cnt21, ptr12, ptr21, cur12, cur21);
    fill_kernel<<<eb, 256, 0, stream>>>(e12, e21, cur12, cur21, rc12, rc21);

    // input linear + relu fused with layer-0 K/Q/V (x lives only in LDS)
    in_kqv<<<dim3(NN / 16, 1, 2), 256, 0, stream>>>(
        x_n1, x_n2, Win, b_in, Wk, Wq, Wv, bk, bq, bv, Kh, Qh, Vh);

    conv_fused<<<dim3(NN / 8 * 2), 256, 0, stream>>>(
        ptr12, rc12, ptr21, rc21, Kh, Qh, Vh, ew, aggb, sums, 0);

    // out GEMM layer 0 fused with layer-1 K/Q/V
    out_kqv<<<dim3(NN / 16, 1, 2), 256, 0, stream>>>(
        aggb, Wout, bout, sums, 0, Wk, Wq, Wv, bk, bq, bv, Kh, Qh, Vh, Emh2, Edh2);

    conv_fused<<<dim3(NN / 8 * 2), 256, 0, stream>>>(
        ptr12, rc12, ptr21, rc21, Kh, Qh, Vh, ew, aggb, sums, 1);

    out_last<<<dim3(NN / 16, 1, 2), 256, 0, stream>>>(
        aggb, Wout, bout, sums, 1, Emh2, Edh2);

    pred_kernel<<<(NP * 8 + 255) / 256, 256, 0, stream>>>(
        (const __half*)Emh2, (const __half*)Edh2, pe, out);
}

// Round 15
// 221.130 us; speedup vs baseline: 1.0916x; 1.0038x over previous
//
#include <hip/hip_runtime.h>
#include <hip/hip_fp16.h>

#define NN 10000
#define DIN 128
#define HD 64
#define HH 128          // H*HEADS
#define NE 250000
#define NP 100000

typedef _Float16 h2v __attribute__((ext_vector_type(2)));

// ---------------- CSR build ----------------

__global__ void count_kernel(const int* e12, const int* e21, int* cnt12, int* cnt21) {
    int t = blockIdx.x * blockDim.x + threadIdx.x;
    if (t < NE)            atomicAdd(&cnt12[e12[NE + t]], 1);
    else if (t < 2 * NE)   atomicAdd(&cnt21[e21[NE + (t - NE)]], 1);
}

__global__ void scan_kernel(const int* cnt12, const int* cnt21,
                            int* ptr12, int* ptr21, int* cur12, int* cur21) {
    const int* cnt = blockIdx.x ? cnt21 : cnt12;
    int* ptr = blockIdx.x ? ptr21 : ptr12;
    int* cur = blockIdx.x ? cur21 : cur12;
    const int T = 1024, C = 10;                 // 1024*10 = 10240 >= 10000
    __shared__ int sm[1024];
    int t = threadIdx.x;
    int v[C]; int tot = 0;
    int base = t * C;
    #pragma unroll
    for (int i = 0; i < C; i++) {
        int id = base + i;
        v[i] = (id < NN) ? cnt[id] : 0;
        tot += v[i];
    }
    sm[t] = tot; __syncthreads();
    for (int off = 1; off < T; off <<= 1) {
        int x = (t >= off) ? sm[t - off] : 0;
        __syncthreads();
        sm[t] += x;
        __syncthreads();
    }
    int run = sm[t] - tot;                      // exclusive prefix
    #pragma unroll
    for (int i = 0; i < C; i++) {
        int id = base + i;
        if (id < NN) { ptr[id] = run; cur[id] = run; }
        run += v[i];
    }
    if (t == T - 1) ptr[NN] = run;
}

// writes packed (row, col) per CSR slot
__global__ void fill_kernel(const int* e12, const int* e21,
                            int* cur12, int* cur21, int2* rc12, int2* rc21) {
    int t = blockIdx.x * blockDim.x + threadIdx.x;
    if (t < NE) {
        int c = e12[NE + t];
        int p = atomicAdd(&cur12[c], 1);
        rc12[p] = make_int2(e12[t], c);
    } else if (t < 2 * NE) {
        int e = t - NE;
        int c = e21[NE + e];
        int p = atomicAdd(&cur21[c], 1);
        rc21[p] = make_int2(e21[e], c);
    }
}

// ---------------- shared device pieces ----------------

__device__ __forceinline__ float dotc(const uint4& k, const uint4& q) {
#if __has_builtin(__builtin_amdgcn_fdot2)
    const h2v* kh = (const h2v*)&k;
    const h2v* qh = (const h2v*)&q;
    float s = 0.f;
    #pragma unroll
    for (int i = 0; i < 4; i++)
        s = __builtin_amdgcn_fdot2(kh[i], qh[i], s, false);
    return s;
#else
    const __half2* kh = (const __half2*)&k;
    const __half2* qh = (const __half2*)&q;
    float s = 0.f;
    #pragma unroll
    for (int i = 0; i < 4; i++) {
        float2 a = __half22float2(kh[i]);
        float2 b = __half22float2(qh[i]);
        s += a.x * b.x + a.y * b.y;
    }
    return s;
#endif
}
__device__ __forceinline__ void acc8(const uint4& v, float e, float* acc) {
    const __half2* h = (const __half2*)&v;
    float2 f0 = __half22float2(h[0]), f1 = __half22float2(h[1]);
    float2 f2 = __half22float2(h[2]), f3 = __half22float2(h[3]);
    acc[0] += e*f0.x; acc[1] += e*f0.y; acc[2] += e*f1.x; acc[3] += e*f1.y;
    acc[4] += e*f2.x; acc[5] += e*f2.y; acc[6] += e*f3.x; acc[7] += e*f3.y;
}

// 3 K/Q/V GEMM phases over the block's 16 x-rows held in LDS (Xs, 16x64 f32).
// node type z: K,V -> rel=z ; Q -> rel=1-z. W staged in Ws (32 KB) per phase.
__device__ __forceinline__ void kqv_phases(
        int z, int l, const float* Xs, float4* Ws4, int row0, int tid,
        const float* __restrict__ Wk, const float* __restrict__ Wq,
        const float* __restrict__ Wv,
        const float* __restrict__ bk, const float* __restrict__ bq,
        const float* __restrict__ bv,
        __half* Kh, __half* Qh, __half* Vh) {
    #pragma unroll
    for (int kind = 0; kind < 3; kind++) {
        int rel = (kind == 1) ? (1 - z) : z;
        size_t wo = (size_t)(l * 2 + rel) * HD * HH;
        size_t bo = (size_t)(l * 2 + rel) * HH;
        const float4* W4 = (const float4*)((kind == 0 ? Wk : kind == 1 ? Wq : Wv) + wo);
        const float4* b4 = (const float4*)((kind == 0 ? bk : kind == 1 ? bq : bv) + bo);
        #pragma unroll
        for (int i = 0; i < 8; i++) Ws4[tid + 256 * i] = W4[tid + 256 * i];
        __syncthreads();
        int cg = tid & 31, rg = tid >> 5;       // rg 0..7, rows rg*2, rg*2+1
        float4 acc0 = b4[cg], acc1 = acc0;
        const float* a0 = &Xs[(rg * 2) * HD];
        const float* a1 = &Xs[(rg * 2 + 1) * HD];
        for (int k = 0; k < HD; k++) {
            float4 w = Ws4[k * 32 + cg];
            float v0 = a0[k], v1 = a1[k];
            acc0.x += v0 * w.x; acc0.y += v0 * w.y; acc0.z += v0 * w.z; acc0.w += v0 * w.w;
            acc1.x += v1 * w.x; acc1.y += v1 * w.y; acc1.z += v1 * w.z; acc1.w += v1 * w.w;
        }
        __half* dst = (kind == 0) ? Kh : (kind == 1) ? Qh : Vh;
        int node = row0 + rg * 2;
        {
            __half2* H2 = (__half2*)(dst + (size_t)rel * NN * HH + (size_t)node * HH + cg * 4);
            float2 lo = {acc0.x, acc0.y}, hi = {acc0.z, acc0.w};
            H2[0] = __float22half2_rn(lo);
            H2[1] = __float22half2_rn(hi);
        }
        {
            __half2* H2 = (__half2*)(dst + (size_t)rel * NN * HH + (size_t)(node + 1) * HH + cg * 4);
            float2 lo = {acc1.x, acc1.y}, hi = {acc1.z, acc1.w};
            H2[0] = __float22half2_rn(lo);
            H2[1] = __float22half2_rn(hi);
        }
        __syncthreads();                        // Ws reads done before next staging
    }
}

// ---------------- fused: input GEMM + layer-0 K/Q/V ----------------
__global__ __launch_bounds__(256) void in_kqv(
        const float* __restrict__ xn1, const float* __restrict__ xn2,
        const float* __restrict__ Win, const float* __restrict__ b_in,
        const float* __restrict__ Wk, const float* __restrict__ Wq,
        const float* __restrict__ Wv,
        const float* __restrict__ bk, const float* __restrict__ bq,
        const float* __restrict__ bv,
        __half* Kh, __half* Qh, __half* Vh) {
    int z = blockIdx.z;
    int tid = threadIdx.x;
    int row0 = blockIdx.x * 16;
    __shared__ float As[16 * DIN];              // 8 KB
    __shared__ float Ws[DIN * HD];              // 32 KB
    __shared__ float Xs[16 * HD];               // 4 KB
    float4* As4 = (float4*)As;
    float4* Ws4 = (float4*)Ws;
    float4* Xs4 = (float4*)Xs;
    {
        const float4* A4 = (const float4*)(z ? xn2 : xn1);
        const float4* W4 = (const float4*)(Win + (size_t)z * DIN * HD);
        const float4* b4 = (const float4*)(b_in + (size_t)z * HD);
        As4[tid]       = A4[(size_t)row0 * 32 + tid];
        As4[tid + 256] = A4[(size_t)row0 * 32 + tid + 256];
        #pragma unroll
        for (int i = 0; i < 8; i++) Ws4[tid + 256 * i] = W4[tid + 256 * i];
        __syncthreads();
        int r = tid >> 4, cg = tid & 15;
        float4 acc = b4[cg];
        const float* a = &As[r * DIN];
        for (int k = 0; k < DIN; k++) {
            float av = a[k];
            float4 w = Ws4[k * 16 + cg];
            acc.x += av * w.x; acc.y += av * w.y; acc.z += av * w.z; acc.w += av * w.w;
        }
        acc.x = fmaxf(acc.x, 0.f); acc.y = fmaxf(acc.y, 0.f);
        acc.z = fmaxf(acc.z, 0.f); acc.w = fmaxf(acc.w, 0.f);
        Xs4[r * 16 + cg] = acc;
        __syncthreads();
    }
    kqv_phases(z, 0, Xs, Ws4, row0, tid, Wk, Wq, Wv, bk, bq, bv, Kh, Qh, Vh);
}

// ---------------- fused: out GEMM (layer l) + K/Q/V (layer l+1) ----------------
__global__ __launch_bounds__(256) void out_kqv(
        const float* __restrict__ aggb,
        const float* __restrict__ Wout, const float* __restrict__ bout,
        const float* __restrict__ sums, int l,
        const float* __restrict__ Wk, const float* __restrict__ Wq,
        const float* __restrict__ Wv,
        const float* __restrict__ bk, const float* __restrict__ bq,
        const float* __restrict__ bv,
        __half* Kh, __half* Qh, __half* Vh,
        __half2* Emh2, __half2* Edh2) {
    int z = blockIdx.z;
    int sel = z ? 0 : 1;                        // which relation's aggregate
    int tid = threadIdx.x;
    int row0 = blockIdx.x * 16;
    __shared__ float As[16 * HH];               // 8 KB
    __shared__ float Ws[HH * HD];               // 32 KB
    __shared__ float Xs[16 * HD];               // 4 KB
    __shared__ float invs[2];
    float4* As4 = (float4*)As;
    float4* Ws4 = (float4*)Ws;
    float4* Xs4 = (float4*)Xs;
    {
        const float4* A4 = (const float4*)(aggb + (size_t)sel * NN * HH);
        const float4* W4 = (const float4*)(Wout + (size_t)(l * 2 + z) * HH * HD);
        const float4* b4 = (const float4*)(bout + (size_t)(l * 2 + z) * HD);
        __half2* E2 = z ? Edh2 : Emh2;
        if (tid < 128) {
            int h = tid >> 6;
            float v = sums[l * 256 + sel * 128 + h * 64 + (tid & 63)];
            #pragma unroll
            for (int off = 1; off <= 32; off <<= 1) v += __shfl_xor(v, off);
            if ((tid & 63) == 0) invs[h] = 1.f / v;
        }
        __syncthreads();
        float inv0 = invs[0], inv1 = invs[1];
        {
            float4 t0 = A4[(size_t)row0 * 32 + tid];
            float4 t1 = A4[(size_t)row0 * 32 + tid + 256];
            float s0 = ((tid & 31) < 16) ? inv0 : inv1;   // cols 0-63 = head0
            t0.x *= s0; t0.y *= s0; t0.z *= s0; t0.w *= s0;
            t1.x *= s0; t1.y *= s0; t1.z *= s0; t1.w *= s0;
            As4[tid] = t0; As4[tid + 256] = t1;
        }
        #pragma unroll
        for (int i = 0; i < 8; i++) Ws4[tid + 256 * i] = W4[tid + 256 * i];
        __syncthreads();
        int r = tid >> 4, cg = tid & 15;
        float4 acc = b4[cg];
        const float* a = &As[r * HH];
        for (int k = 0; k < HH; k++) {
            float av = a[k];
            float4 w = Ws4[k * 16 + cg];
            acc.x += av * w.x; acc.y += av * w.y; acc.z += av * w.z; acc.w += av * w.w;
        }
        int node = row0 + r;
        Xs4[r * 16 + cg] = acc;
        float2 lo = {acc.x, acc.y}, hi = {acc.z, acc.w};
        E2[(size_t)node * 64 + l * 32 + cg * 2]     = __float22half2_rn(lo);
        E2[(size_t)node * 64 + l * 32 + cg * 2 + 1] = __float22half2_rn(hi);
        __syncthreads();
    }
    kqv_phases(z, l + 1, Xs, Ws4, row0, tid, Wk, Wq, Wv, bk, bq, bv, Kh, Qh, Vh);
}

// ---------------- final out GEMM (layer 1; Em/Ed only) ----------------
__global__ __launch_bounds__(256) void out_last(
        const float* __restrict__ aggb,
        const float* __restrict__ Wout, const float* __restrict__ bout,
        const float* __restrict__ sums, int l,
        __half2* Emh2, __half2* Edh2) {
    int z = blockIdx.z;
    int sel = z ? 0 : 1;
    const float4* A4 = (const float4*)(aggb + (size_t)sel * NN * HH);
    const float4* W4 = (const float4*)(Wout + (size_t)(l * 2 + z) * HH * HD);
    const float4* b4 = (const float4*)(bout + (size_t)(l * 2 + z) * HD);
    __half2* E2 = z ? Edh2 : Emh2;
    __shared__ float As[16 * HH];
    __shared__ float Ws[HH * HD];
    __shared__ float invs[2];
    int tid = threadIdx.x;
    if (tid < 128) {
        int h = tid >> 6;
        float v = sums[l * 256 + sel * 128 + h * 64 + (tid & 63)];
        #pragma unroll
        for (int off = 1; off <= 32; off <<= 1) v += __shfl_xor(v, off);
        if ((tid & 63) == 0) invs[h] = 1.f / v;
    }
    __syncthreads();
    float inv0 = invs[0], inv1 = invs[1];
    int row0 = blockIdx.x * 16;
    float4* As4 = (float4*)As;
    float4* Ws4 = (float4*)Ws;
    {
        float4 t0 = A4[(size_t)row0 * 32 + tid];
        float4 t1 = A4[(size_t)row0 * 32 + tid + 256];
        float s0 = ((tid & 31) < 16) ? inv0 : inv1;
        t0.x *= s0; t0.y *= s0; t0.z *= s0; t0.w *= s0;
        t1.x *= s0; t1.y *= s0; t1.z *= s0; t1.w *= s0;
        As4[tid] = t0; As4[tid + 256] = t1;
    }
    #pragma unroll
    for (int i = 0; i < 8; i++) Ws4[tid + 256 * i] = W4[tid + 256 * i];
    __syncthreads();
    int r = tid >> 4, cg = tid & 15;
    float4 acc = b4[cg];
    const float* a = &As[r * HH];
    for (int k = 0; k < HH; k++) {
        float av = a[k];
        float4 w = Ws4[k * 16 + cg];
        acc.x += av * w.x; acc.y += av * w.y; acc.z += av * w.z; acc.w += av * w.w;
    }
    int node = row0 + r;
    float2 lo = {acc.x, acc.y}, hi = {acc.z, acc.w};
    E2[(size_t)node * 64 + l * 32 + cg * 2]     = __float22half2_rn(lo);
    E2[(size_t)node * 64 + l * 32 + cg * 2 + 1] = __float22half2_rn(hi);
}

// ---------------- fused attention: block = (rel, 8 dest nodes) ----------------
__global__ __launch_bounds__(256) void conv_fused(
        const int* __restrict__ ptr12, const int2* __restrict__ rc12,
        const int* __restrict__ ptr21, const int2* __restrict__ rc21,
        const __half* __restrict__ Kh, const __half* __restrict__ Qh,
        const __half* __restrict__ Vh,
        float* __restrict__ ew, float* __restrict__ aggb,
        float* __restrict__ sums, int l) {
    int b = blockIdx.x;
    int rel = b & 1, seg = b >> 1;              // seg in [0, 1250)
    const int* __restrict__ ptr = rel ? ptr21 : ptr12;
    const int2* __restrict__ rc = rel ? rc21 : rc12;
    const uint4* K = (const uint4*)(Kh + (size_t)rel * NN * HH);
    const uint4* Q = (const uint4*)(Qh + (size_t)rel * NN * HH);
    const uint4* V = (const uint4*)(Vh + (size_t)rel * NN * HH);
    float* __restrict__ ew0 = ew + (size_t)rel * 2 * NE;
    float* __restrict__ ew1 = ew0 + NE;
    float4* A4 = (float4*)(aggb + (size_t)rel * NN * HH);
    int tid = threadIdx.x;
    int c0 = seg * 8;
    int jb0 = ptr[c0], je0 = ptr[c0 + 8];

    // ---- phase A: 8-lane group per edge, fdot2 dot products ----
    int s8 = tid & 7;
    float s0 = 0.f, s1 = 0.f;
    for (int j = jb0 + (tid >> 3); j < je0; j += 32) {
        int2 e = rc[j];
        uint4 k0 = K[(size_t)e.x * 16 + s8];
        uint4 k1 = K[(size_t)e.x * 16 + 8 + s8];
        uint4 q0 = Q[(size_t)e.y * 16 + s8];
        uint4 q1 = Q[(size_t)e.y * 16 + 8 + s8];
        float p0 = dotc(k0, q0);
        float p1 = dotc(k1, q1);
        #pragma unroll
        for (int off = 1; off <= 4; off <<= 1) {
            p0 += __shfl_xor(p0, off);
            p1 += __shfl_xor(p1, off);
        }
        p0 *= 0.125f; p1 *= 0.125f;
        p0 = p0 > 0.f ? p0 : 0.2f * p0;
        p1 = p1 > 0.f ? p1 : 0.2f * p1;
        float e0 = __expf(p0), e1 = __expf(p1);
        if (s8 == 0) {
            ew0[j] = e0; ew1[j] = e1;
            s0 += e0; s1 += e1;
        }
    }
    #pragma unroll
    for (int off = 8; off <= 32; off <<= 1) {
        s0 += __shfl_xor(s0, off);
        s1 += __shfl_xor(s1, off);
    }
    __shared__ float sred[4][2];
    int wave = tid >> 6, lane = tid & 63;
    if (lane == 0) { sred[wave][0] = s0; sred[wave][1] = s1; }
    __syncthreads();                            // also publishes ew to the block
    if (tid < 2) {
        float t = sred[0][tid] + sred[1][tid] + sred[2][tid] + sred[3][tid];
        atomicAdd(&sums[l * 256 + rel * 128 + tid * 64 + (seg & 63)], t);
    }

    // ---- phase B: 4 waves x 2 nodes each ----
    int g = lane >> 4, sl = lane & 15;
    const float* __restrict__ wp = ew0 + (size_t)(sl >> 3) * NE;   // head plane
    #pragma unroll
    for (int ni = 0; ni < 2; ni++) {
        int c = c0 + wave * 2 + ni;
        float acc[8] = {0,0,0,0,0,0,0,0};
        int jb = ptr[c], je = ptr[c + 1];
        int o = jb + g;
        int r0 = (o      < je) ? rc[o].x      : -1;
        int r1 = (o + 4  < je) ? rc[o + 4].x  : -1;
        int r2 = (o + 8  < je) ? rc[o + 8].x  : -1;
        int r3 = (o + 12 < je) ? rc[o + 12].x : -1;
        for (int j = o; j < je; j += 16) {
            int n0 = (j + 16 < je) ? rc[j + 16].x : -1;
            int n1 = (j + 20 < je) ? rc[j + 20].x : -1;
            int n2 = (j + 24 < je) ? rc[j + 24].x : -1;
            int n3 = (j + 28 < je) ? rc[j + 28].x : -1;
            float w0 = (r0 >= 0) ? wp[j]      : 0.f;
            float w1 = (r1 >= 0) ? wp[j + 4]  : 0.f;
            float w2 = (r2 >= 0) ? wp[j + 8]  : 0.f;
            float w3 = (r3 >= 0) ? wp[j + 12] : 0.f;
            uint4 v0 = V[(size_t)(r0 >= 0 ? r0 : 0) * 16 + sl];
            uint4 v1 = V[(size_t)(r1 >= 0 ? r1 : 0) * 16 + sl];
            uint4 v2 = V[(size_t)(r2 >= 0 ? r2 : 0) * 16 + sl];
            uint4 v3 = V[(size_t)(r3 >= 0 ? r3 : 0) * 16 + sl];
            acc8(v0, w0, acc); acc8(v1, w1, acc);
            acc8(v2, w2, acc); acc8(v3, w3, acc);
            r0 = n0; r1 = n1; r2 = n2; r3 = n3;
        }
        #pragma unroll
        for (int i = 0; i < 8; i++) {
            acc[i] += __shfl_xor(acc[i], 16);
            acc[i] += __shfl_xor(acc[i], 32);
        }
        if (g == 0) {
            float4 t0 = {acc[0], acc[1], acc[2], acc[3]};
            float4 t1 = {acc[4], acc[5], acc[6], acc[7]};
            A4[(size_t)c * 32 + 2 * sl]     = t0;
            A4[(size_t)c * 32 + 2 * sl + 1] = t1;
        }
    }
}

// ---------------- prediction (8-lane group per pair, fdot2) ----------------
__global__ __launch_bounds__(256) void pred_kernel(
        const __half* __restrict__ Emh, const __half* __restrict__ Edh,
        const int* __restrict__ pe, float* out) {
    int grp = (blockIdx.x * 256 + threadIdx.x) >> 3;   // pair index
    int s8 = threadIdx.x & 7;
    if (grp >= NP) return;
    int m = pe[grp], d = pe[NP + grp];
    const uint4* a = (const uint4*)Emh + (size_t)m * 16;
    const uint4* b = (const uint4*)Edh + (size_t)d * 16;
    float acc = dotc(a[s8], b[s8]) + dotc(a[8 + s8], b[8 + s8]);
    #pragma unroll
    for (int off = 1; off <= 4; off <<= 1) acc += __shfl_xor(acc, off);
    if (s8 == 0) out[grp] = acc;
}

// ---------------- host ----------------

extern "C" void kernel_launch(void* const* d_in, const int* in_sizes, int n_in,
                              void* d_out, int out_size, void* d_ws, size_t ws_size,
                              hipStream_t stream) {
    (void)in_sizes; (void)n_in; (void)out_size; (void)ws_size;
    const float* x_n1 = (const float*)d_in[0];
    const float* x_n2 = (const float*)d_in[1];
    const int*   e12  = (const int*)d_in[2];
    const int*   e21  = (const int*)d_in[3];
    const int*   pe   = (const int*)d_in[4];
    const float* Win  = (const float*)d_in[5];
    const float* b_in = (const float*)d_in[6];
    const float* Wk   = (const float*)d_in[7];
    const float* bk   = (const float*)d_in[8];
    const float* Wq   = (const float*)d_in[9];
    const float* bq   = (const float*)d_in[10];
    const float* Wv   = (const float*)d_in[11];
    const float* bv   = (const float*)d_in[12];
    const float* Wout = (const float*)d_in[13];
    const float* bout = (const float*)d_in[14];
    float* out = (float*)d_out;

    char* w = (char*)d_ws;
    auto carve = [&](size_t nbytes) -> void* {
        void* p = (void*)w;
        w += (nbytes + 255) & ~(size_t)255;
        return p;
    };
    __half* Kh   = (__half*)carve((size_t)2 * NN * HH * 2);
    __half* Qh   = (__half*)carve((size_t)2 * NN * HH * 2);
    __half* Vh   = (__half*)carve((size_t)2 * NN * HH * 2);
    float* ew    = (float*)carve((size_t)2 * 2 * NE * 4);
    float* aggb  = (float*)carve((size_t)2 * NN * HH * 4);
    __half2* Emh2 = (__half2*)carve((size_t)NN * HH * 2);
    __half2* Edh2 = (__half2*)carve((size_t)NN * HH * 2);
    int* cnt     = (int*)carve((size_t)2 * NN * 4);    // cnt + sums: one memset
    float* sums  = (float*)carve((size_t)2 * 256 * 4);
    int* cur12   = (int*)carve((size_t)NN * 4);
    int* cur21   = (int*)carve((size_t)NN * 4);
    int* ptr12   = (int*)carve((size_t)(NN + 1) * 4);
    int* ptr21   = (int*)carve((size_t)(NN + 1) * 4);
    int2* rc12   = (int2*)carve((size_t)NE * 8);
    int2* rc21   = (int2*)carve((size_t)NE * 8);
    int* cnt12 = cnt;
    int* cnt21 = cnt + NN;

    // zero cnt + sums (adjacent carves) in one memset
    size_t zbytes = (((size_t)2 * NN * 4 + 255) & ~(size_t)255) + (size_t)2 * 256 * 4;
    hipMemsetAsync(cnt, 0, zbytes, stream);

    // CSR build
    int eb = (2 * NE + 255) / 256;
    count_kernel<<<eb, 256, 0, stream>>>(e12, e21, cnt12, cnt21);
    scan_kernel<<<2, 1024, 0, stream>>>(cnt12, cnt21, ptr12, ptr21, cur12, cur21);
    fill_kernel<<<eb, 256, 0, stream>>>(e12, e21, cur12, cur21, rc12, rc21);

    // input linear + relu fused with layer-0 K/Q/V (x lives only in LDS)
    in_kqv<<<dim3(NN / 16, 1, 2), 256, 0, stream>>>(
        x_n1, x_n2, Win, b_in, Wk, Wq, Wv, bk, bq, bv, Kh, Qh, Vh);

    conv_fused<<<dim3(NN / 8 * 2), 256, 0, stream>>>(
        ptr12, rc12, ptr21, rc21, Kh, Qh, Vh, ew, aggb, sums, 0);

    // out GEMM layer 0 fused with layer-1 K/Q/V
    out_kqv<<<dim3(NN / 16, 1, 2), 256, 0, stream>>>(
        aggb, Wout, bout, sums, 0, Wk, Wq, Wv, bk, bq, bv, Kh, Qh, Vh, Emh2, Edh2);

    conv_fused<<<dim3(NN / 8 * 2), 256, 0, stream>>>(
        ptr12, rc12, ptr21, rc21, Kh, Qh, Vh, ew, aggb, sums, 1);

    out_last<<<dim3(NN / 16, 1, 2), 256, 0, stream>>>(
        aggb, Wout, bout, sums, 1, Emh2, Edh2);

    pred_kernel<<<(NP * 8 + 255) / 256, 256, 0, stream>>>(
        (const __half*)Emh2, (const __half*)Edh2, pe, out);
}

// Round 16
// 216.865 us; speedup vs baseline: 1.1131x; 1.0197x over previous
//
#include <hip/hip_runtime.h>
#include <hip/hip_fp16.h>

#define NN 10000
#define DIN 128
#define HD 64
#define HH 128          // H*HEADS
#define NE 250000
#define NP 100000

typedef _Float16 h2v __attribute__((ext_vector_type(2)));

// ---------------- CSR build ----------------

// int4-vectorized: 4 cols per thread
__global__ void count_kernel(const int* e12, const int* e21, int* cnt12, int* cnt21) {
    int t = blockIdx.x * blockDim.x + threadIdx.x;
    if (t < NE / 4) {
        int4 c = ((const int4*)(e12 + NE))[t];
        atomicAdd(&cnt12[c.x], 1); atomicAdd(&cnt12[c.y], 1);
        atomicAdd(&cnt12[c.z], 1); atomicAdd(&cnt12[c.w], 1);
    } else if (t < NE / 2) {
        int4 c = ((const int4*)(e21 + NE))[t - NE / 4];
        atomicAdd(&cnt21[c.x], 1); atomicAdd(&cnt21[c.y], 1);
        atomicAdd(&cnt21[c.z], 1); atomicAdd(&cnt21[c.w], 1);
    }
}

__global__ void scan_kernel(const int* cnt12, const int* cnt21,
                            int* ptr12, int* ptr21, int* cur12, int* cur21) {
    const int* cnt = blockIdx.x ? cnt21 : cnt12;
    int* ptr = blockIdx.x ? ptr21 : ptr12;
    int* cur = blockIdx.x ? cur21 : cur12;
    const int T = 1024, C = 10;                 // 1024*10 = 10240 >= 10000
    __shared__ int sm[1024];
    int t = threadIdx.x;
    int v[C]; int tot = 0;
    int base = t * C;
    #pragma unroll
    for (int i = 0; i < C; i++) {
        int id = base + i;
        v[i] = (id < NN) ? cnt[id] : 0;
        tot += v[i];
    }
    sm[t] = tot; __syncthreads();
    for (int off = 1; off < T; off <<= 1) {
        int x = (t >= off) ? sm[t - off] : 0;
        __syncthreads();
        sm[t] += x;
        __syncthreads();
    }
    int run = sm[t] - tot;                      // exclusive prefix
    #pragma unroll
    for (int i = 0; i < C; i++) {
        int id = base + i;
        if (id < NN) { ptr[id] = run; cur[id] = run; }
        run += v[i];
    }
    if (t == T - 1) ptr[NN] = run;
}

// writes packed (row, col) per CSR slot
__global__ void fill_kernel(const int* e12, const int* e21,
                            int* cur12, int* cur21, int2* rc12, int2* rc21) {
    int t = blockIdx.x * blockDim.x + threadIdx.x;
    if (t < NE) {
        int c = e12[NE + t];
        int p = atomicAdd(&cur12[c], 1);
        rc12[p] = make_int2(e12[t], c);
    } else if (t < 2 * NE) {
        int e = t - NE;
        int c = e21[NE + e];
        int p = atomicAdd(&cur21[c], 1);
        rc21[p] = make_int2(e21[e], c);
    }
}

// ---------------- shared device pieces ----------------

__device__ __forceinline__ float dotc(const uint4& k, const uint4& q) {
#if __has_builtin(__builtin_amdgcn_fdot2)
    const h2v* kh = (const h2v*)&k;
    const h2v* qh = (const h2v*)&q;
    float s = 0.f;
    #pragma unroll
    for (int i = 0; i < 4; i++)
        s = __builtin_amdgcn_fdot2(kh[i], qh[i], s, false);
    return s;
#else
    const __half2* kh = (const __half2*)&k;
    const __half2* qh = (const __half2*)&q;
    float s = 0.f;
    #pragma unroll
    for (int i = 0; i < 4; i++) {
        float2 a = __half22float2(kh[i]);
        float2 b = __half22float2(qh[i]);
        s += a.x * b.x + a.y * b.y;
    }
    return s;
#endif
}
__device__ __forceinline__ void acc8(const uint4& v, float e, float* acc) {
    const __half2* h = (const __half2*)&v;
    float2 f0 = __half22float2(h[0]), f1 = __half22float2(h[1]);
    float2 f2 = __half22float2(h[2]), f3 = __half22float2(h[3]);
    acc[0] += e*f0.x; acc[1] += e*f0.y; acc[2] += e*f1.x; acc[3] += e*f1.y;
    acc[4] += e*f2.x; acc[5] += e*f2.y; acc[6] += e*f3.x; acc[7] += e*f3.y;
}

// 3 K/Q/V GEMM phases over the block's 16 x-rows held in LDS (Xs, 16x64 f32).
// node type z: K,V -> rel=z ; Q -> rel=1-z. W staged in Ws (32 KB) per phase.
__device__ __forceinline__ void kqv_phases(
        int z, int l, const float* Xs, float4* Ws4, int row0, int tid,
        const float* __restrict__ Wk, const float* __restrict__ Wq,
        const float* __restrict__ Wv,
        const float* __restrict__ bk, const float* __restrict__ bq,
        const float* __restrict__ bv,
        __half* Kh, __half* Qh, __half* Vh) {
    #pragma unroll
    for (int kind = 0; kind < 3; kind++) {
        int rel = (kind == 1) ? (1 - z) : z;
        size_t wo = (size_t)(l * 2 + rel) * HD * HH;
        size_t bo = (size_t)(l * 2 + rel) * HH;
        const float4* W4 = (const float4*)((kind == 0 ? Wk : kind == 1 ? Wq : Wv) + wo);
        const float4* b4 = (const float4*)((kind == 0 ? bk : kind == 1 ? bq : bv) + bo);
        #pragma unroll
        for (int i = 0; i < 8; i++) Ws4[tid + 256 * i] = W4[tid + 256 * i];
        __syncthreads();
        int cg = tid & 31, rg = tid >> 5;       // rg 0..7, rows rg*2, rg*2+1
        float4 acc0 = b4[cg], acc1 = acc0;
        const float* a0 = &Xs[(rg * 2) * HD];
        const float* a1 = &Xs[(rg * 2 + 1) * HD];
        for (int k = 0; k < HD; k++) {
            float4 w = Ws4[k * 32 + cg];
            float v0 = a0[k], v1 = a1[k];
            acc0.x += v0 * w.x; acc0.y += v0 * w.y; acc0.z += v0 * w.z; acc0.w += v0 * w.w;
            acc1.x += v1 * w.x; acc1.y += v1 * w.y; acc1.z += v1 * w.z; acc1.w += v1 * w.w;
        }
        __half* dst = (kind == 0) ? Kh : (kind == 1) ? Qh : Vh;
        int node = row0 + rg * 2;
        {
            __half2* H2 = (__half2*)(dst + (size_t)rel * NN * HH + (size_t)node * HH + cg * 4);
            float2 lo = {acc0.x, acc0.y}, hi = {acc0.z, acc0.w};
            H2[0] = __float22half2_rn(lo);
            H2[1] = __float22half2_rn(hi);
        }
        {
            __half2* H2 = (__half2*)(dst + (size_t)rel * NN * HH + (size_t)(node + 1) * HH + cg * 4);
            float2 lo = {acc1.x, acc1.y}, hi = {acc1.z, acc1.w};
            H2[0] = __float22half2_rn(lo);
            H2[1] = __float22half2_rn(hi);
        }
        __syncthreads();                        // Ws reads done before next staging
    }
}

// ---------------- fused: input GEMM + layer-0 K/Q/V ----------------
__global__ __launch_bounds__(256) void in_kqv(
        const float* __restrict__ xn1, const float* __restrict__ xn2,
        const float* __restrict__ Win, const float* __restrict__ b_in,
        const float* __restrict__ Wk, const float* __restrict__ Wq,
        const float* __restrict__ Wv,
        const float* __restrict__ bk, const float* __restrict__ bq,
        const float* __restrict__ bv,
        __half* Kh, __half* Qh, __half* Vh) {
    int z = blockIdx.z;
    int tid = threadIdx.x;
    int row0 = blockIdx.x * 16;
    __shared__ float As[16 * DIN];              // 8 KB
    __shared__ float Ws[DIN * HD];              // 32 KB
    __shared__ float Xs[16 * HD];               // 4 KB
    float4* As4 = (float4*)As;
    float4* Ws4 = (float4*)Ws;
    float4* Xs4 = (float4*)Xs;
    {
        const float4* A4 = (const float4*)(z ? xn2 : xn1);
        const float4* W4 = (const float4*)(Win + (size_t)z * DIN * HD);
        const float4* b4 = (const float4*)(b_in + (size_t)z * HD);
        As4[tid]       = A4[(size_t)row0 * 32 + tid];
        As4[tid + 256] = A4[(size_t)row0 * 32 + tid + 256];
        #pragma unroll
        for (int i = 0; i < 8; i++) Ws4[tid + 256 * i] = W4[tid + 256 * i];
        __syncthreads();
        int r = tid >> 4, cg = tid & 15;
        float4 acc = b4[cg];
        const float* a = &As[r * DIN];
        for (int k = 0; k < DIN; k++) {
            float av = a[k];
            float4 w = Ws4[k * 16 + cg];
            acc.x += av * w.x; acc.y += av * w.y; acc.z += av * w.z; acc.w += av * w.w;
        }
        acc.x = fmaxf(acc.x, 0.f); acc.y = fmaxf(acc.y, 0.f);
        acc.z = fmaxf(acc.z, 0.f); acc.w = fmaxf(acc.w, 0.f);
        Xs4[r * 16 + cg] = acc;
        __syncthreads();
    }
    kqv_phases(z, 0, Xs, Ws4, row0, tid, Wk, Wq, Wv, bk, bq, bv, Kh, Qh, Vh);
}

// ---------------- fused: out GEMM (layer l) + K/Q/V (layer l+1) ----------------
__global__ __launch_bounds__(256) void out_kqv(
        const float* __restrict__ aggb,
        const float* __restrict__ Wout, const float* __restrict__ bout,
        const float* __restrict__ sums, int l,
        const float* __restrict__ Wk, const float* __restrict__ Wq,
        const float* __restrict__ Wv,
        const float* __restrict__ bk, const float* __restrict__ bq,
        const float* __restrict__ bv,
        __half* Kh, __half* Qh, __half* Vh,
        __half2* Emh2, __half2* Edh2) {
    int z = blockIdx.z;
    int sel = z ? 0 : 1;                        // which relation's aggregate
    int tid = threadIdx.x;
    int row0 = blockIdx.x * 16;
    __shared__ float As[16 * HH];               // 8 KB
    __shared__ float Ws[HH * HD];               // 32 KB
    __shared__ float Xs[16 * HD];               // 4 KB
    __shared__ float invs[2];
    float4* As4 = (float4*)As;
    float4* Ws4 = (float4*)Ws;
    float4* Xs4 = (float4*)Xs;
    {
        const float4* A4 = (const float4*)(aggb + (size_t)sel * NN * HH);
        const float4* W4 = (const float4*)(Wout + (size_t)(l * 2 + z) * HH * HD);
        const float4* b4 = (const float4*)(bout + (size_t)(l * 2 + z) * HD);
        __half2* E2 = z ? Edh2 : Emh2;
        if (tid < 128) {
            int h = tid >> 6;
            float v = sums[l * 256 + sel * 128 + h * 64 + (tid & 63)];
            #pragma unroll
            for (int off = 1; off <= 32; off <<= 1) v += __shfl_xor(v, off);
            if ((tid & 63) == 0) invs[h] = 1.f / v;
        }
        __syncthreads();
        float inv0 = invs[0], inv1 = invs[1];
        {
            float4 t0 = A4[(size_t)row0 * 32 + tid];
            float4 t1 = A4[(size_t)row0 * 32 + tid + 256];
            float s0 = ((tid & 31) < 16) ? inv0 : inv1;   // cols 0-63 = head0
            t0.x *= s0; t0.y *= s0; t0.z *= s0; t0.w *= s0;
            t1.x *= s0; t1.y *= s0; t1.z *= s0; t1.w *= s0;
            As4[tid] = t0; As4[tid + 256] = t1;
        }
        #pragma unroll
        for (int i = 0; i < 8; i++) Ws4[tid + 256 * i] = W4[tid + 256 * i];
        __syncthreads();
        int r = tid >> 4, cg = tid & 15;
        float4 acc = b4[cg];
        const float* a = &As[r * HH];
        for (int k = 0; k < HH; k++) {
            float av = a[k];
            float4 w = Ws4[k * 16 + cg];
            acc.x += av * w.x; acc.y += av * w.y; acc.z += av * w.z; acc.w += av * w.w;
        }
        int node = row0 + r;
        Xs4[r * 16 + cg] = acc;
        float2 lo = {acc.x, acc.y}, hi = {acc.z, acc.w};
        E2[(size_t)node * 64 + l * 32 + cg * 2]     = __float22half2_rn(lo);
        E2[(size_t)node * 64 + l * 32 + cg * 2 + 1] = __float22half2_rn(hi);
        __syncthreads();
    }
    kqv_phases(z, l + 1, Xs, Ws4, row0, tid, Wk, Wq, Wv, bk, bq, bv, Kh, Qh, Vh);
}

// ---------------- final out GEMM (layer 1; Em/Ed only) ----------------
__global__ __launch_bounds__(256) void out_last(
        const float* __restrict__ aggb,
        const float* __restrict__ Wout, const float* __restrict__ bout,
        const float* __restrict__ sums, int l,
        __half2* Emh2, __half2* Edh2) {
    int z = blockIdx.z;
    int sel = z ? 0 : 1;
    const float4* A4 = (const float4*)(aggb + (size_t)sel * NN * HH);
    const float4* W4 = (const float4*)(Wout + (size_t)(l * 2 + z) * HH * HD);
    const float4* b4 = (const float4*)(bout + (size_t)(l * 2 + z) * HD);
    __half2* E2 = z ? Edh2 : Emh2;
    __shared__ float As[16 * HH];
    __shared__ float Ws[HH * HD];
    __shared__ float invs[2];
    int tid = threadIdx.x;
    if (tid < 128) {
        int h = tid >> 6;
        float v = sums[l * 256 + sel * 128 + h * 64 + (tid & 63)];
        #pragma unroll
        for (int off = 1; off <= 32; off <<= 1) v += __shfl_xor(v, off);
        if ((tid & 63) == 0) invs[h] = 1.f / v;
    }
    __syncthreads();
    float inv0 = invs[0], inv1 = invs[1];
    int row0 = blockIdx.x * 16;
    float4* As4 = (float4*)As;
    float4* Ws4 = (float4*)Ws;
    {
        float4 t0 = A4[(size_t)row0 * 32 + tid];
        float4 t1 = A4[(size_t)row0 * 32 + tid + 256];
        float s0 = ((tid & 31) < 16) ? inv0 : inv1;
        t0.x *= s0; t0.y *= s0; t0.z *= s0; t0.w *= s0;
        t1.x *= s0; t1.y *= s0; t1.z *= s0; t1.w *= s0;
        As4[tid] = t0; As4[tid + 256] = t1;
    }
    #pragma unroll
    for (int i = 0; i < 8; i++) Ws4[tid + 256 * i] = W4[tid + 256 * i];
    __syncthreads();
    int r = tid >> 4, cg = tid & 15;
    float4 acc = b4[cg];
    const float* a = &As[r * HH];
    for (int k = 0; k < HH; k++) {
        float av = a[k];
        float4 w = Ws4[k * 16 + cg];
        acc.x += av * w.x; acc.y += av * w.y; acc.z += av * w.z; acc.w += av * w.w;
    }
    int node = row0 + r;
    float2 lo = {acc.x, acc.y}, hi = {acc.z, acc.w};
    E2[(size_t)node * 64 + l * 32 + cg * 2]     = __float22half2_rn(lo);
    E2[(size_t)node * 64 + l * 32 + cg * 2 + 1] = __float22half2_rn(hi);
}

// ---------------- single-pass fused attention: block = (rel, 8 dest nodes) ----
// 8-lane group per edge: loads K,Q,V chunks for the SAME edge, butterfly-reduces
// the dot (all 8 lanes get the sum), computes e in-lane, accumulates e*V into
// 16 per-lane registers. Wave owns 2 nodes; cross-group reduce = 3 shfl steps;
// lanes g==0 write the 128-float agg row. No ew buffer, no second CSR pass.
__global__ __launch_bounds__(256) void conv_fused(
        const int* __restrict__ ptr12, const int2* __restrict__ rc12,
        const int* __restrict__ ptr21, const int2* __restrict__ rc21,
        const __half* __restrict__ Kh, const __half* __restrict__ Qh,
        const __half* __restrict__ Vh,
        float* __restrict__ aggb, float* __restrict__ sums, int l) {
    int b = blockIdx.x;
    int rel = b & 1, seg = b >> 1;              // seg in [0, 1250)
    const int* __restrict__ ptr = rel ? ptr21 : ptr12;
    const int2* __restrict__ rc = rel ? rc21 : rc12;
    const uint4* K = (const uint4*)(Kh + (size_t)rel * NN * HH);
    const uint4* Q = (const uint4*)(Qh + (size_t)rel * NN * HH);
    const uint4* V = (const uint4*)(Vh + (size_t)rel * NN * HH);
    float4* A4 = (float4*)(aggb + (size_t)rel * NN * HH);
    int tid = threadIdx.x;
    int wave = tid >> 6, lane = tid & 63;
    int g = lane >> 3, s8 = lane & 7;           // group 0..7, lane-in-group
    int c0 = seg * 8;
    float s0 = 0.f, s1 = 0.f;
    #pragma unroll
    for (int ni = 0; ni < 2; ni++) {
        int c = c0 + wave * 2 + ni;
        int jb = ptr[c], je = ptr[c + 1];
        float accA[8] = {0,0,0,0,0,0,0,0};
        float accB[8] = {0,0,0,0,0,0,0,0};
        for (int j = jb + g; j < je; j += 8) {
            int2 e = rc[j];
            const uint4* kp = K + (size_t)e.x * 16;
            const uint4* qp = Q + (size_t)e.y * 16;
            const uint4* vp = V + (size_t)e.x * 16;
            uint4 k0 = kp[s8],     q0 = qp[s8],     v0 = vp[s8];
            uint4 k1 = kp[8 + s8], q1 = qp[8 + s8], v1 = vp[8 + s8];
            float p0 = dotc(k0, q0);
            float p1 = dotc(k1, q1);
            #pragma unroll
            for (int off = 1; off <= 4; off <<= 1) {   // butterfly: all 8 lanes get sum
                p0 += __shfl_xor(p0, off);
                p1 += __shfl_xor(p1, off);
            }
            p0 *= 0.125f; p1 *= 0.125f;
            p0 = p0 > 0.f ? p0 : 0.2f * p0;
            p1 = p1 > 0.f ? p1 : 0.2f * p1;
            float e0 = __expf(p0), e1 = __expf(p1);
            acc8(v0, e0, accA);
            acc8(v1, e1, accB);
            if (s8 == 0) { s0 += e0; s1 += e1; }
        }
        // cross-group reduce (groups hold disjoint edge subsets of this node)
        #pragma unroll
        for (int i = 0; i < 8; i++) {
            accA[i] += __shfl_xor(accA[i], 8);
            accA[i] += __shfl_xor(accA[i], 16);
            accA[i] += __shfl_xor(accA[i], 32);
            accB[i] += __shfl_xor(accB[i], 8);
            accB[i] += __shfl_xor(accB[i], 16);
            accB[i] += __shfl_xor(accB[i], 32);
        }
        if (g == 0) {                           // lanes 0..7 write the full row
            float4 a0 = {accA[0], accA[1], accA[2], accA[3]};
            float4 a1 = {accA[4], accA[5], accA[6], accA[7]};
            float4 b0 = {accB[0], accB[1], accB[2], accB[3]};
            float4 b1 = {accB[4], accB[5], accB[6], accB[7]};
            A4[(size_t)c * 32 + 2 * s8]          = a0;
            A4[(size_t)c * 32 + 2 * s8 + 1]      = a1;
            A4[(size_t)c * 32 + 16 + 2 * s8]     = b0;
            A4[(size_t)c * 32 + 16 + 2 * s8 + 1] = b1;
        }
    }
    // exp-sum: only s8==0 lanes nonzero -> butterfly over group bits
    s0 += __shfl_xor(s0, 8);  s0 += __shfl_xor(s0, 16); s0 += __shfl_xor(s0, 32);
    s1 += __shfl_xor(s1, 8);  s1 += __shfl_xor(s1, 16); s1 += __shfl_xor(s1, 32);
    __shared__ float sred[4][2];
    if (lane == 0) { sred[wave][0] = s0; sred[wave][1] = s1; }
    __syncthreads();
    if (tid < 2) {
        float t = sred[0][tid] + sred[1][tid] + sred[2][tid] + sred[3][tid];
        atomicAdd(&sums[l * 256 + rel * 128 + tid * 64 + (seg & 63)], t);
    }
}

// ---------------- prediction (8-lane group per pair, fdot2) ----------------
__global__ __launch_bounds__(256) void pred_kernel(
        const __half* __restrict__ Emh, const __half* __restrict__ Edh,
        const int* __restrict__ pe, float* out) {
    int grp = (blockIdx.x * 256 + threadIdx.x) >> 3;   // pair index
    int s8 = threadIdx.x & 7;
    if (grp >= NP) return;
    int m = pe[grp], d = pe[NP + grp];
    const uint4* a = (const uint4*)Emh + (size_t)m * 16;
    const uint4* b = (const uint4*)Edh + (size_t)d * 16;
    float acc = dotc(a[s8], b[s8]) + dotc(a[8 + s8], b[8 + s8]);
    #pragma unroll
    for (int off = 1; off <= 4; off <<= 1) acc += __shfl_xor(acc, off);
    if (s8 == 0) out[grp] = acc;
}

// ---------------- host ----------------

extern "C" void kernel_launch(void* const* d_in, const int* in_sizes, int n_in,
                              void* d_out, int out_size, void* d_ws, size_t ws_size,
                              hipStream_t stream) {
    (void)in_sizes; (void)n_in; (void)out_size; (void)ws_size;
    const float* x_n1 = (const float*)d_in[0];
    const float* x_n2 = (const float*)d_in[1];
    const int*   e12  = (const int*)d_in[2];
    const int*   e21  = (const int*)d_in[3];
    const int*   pe   = (const int*)d_in[4];
    const float* Win  = (const float*)d_in[5];
    const float* b_in = (const float*)d_in[6];
    const float* Wk   = (const float*)d_in[7];
    const float* bk   = (const float*)d_in[8];
    const float* Wq   = (const float*)d_in[9];
    const float* bq   = (const float*)d_in[10];
    const float* Wv   = (const float*)d_in[11];
    const float* bv   = (const float*)d_in[12];
    const float* Wout = (const float*)d_in[13];
    const float* bout = (const float*)d_in[14];
    float* out = (float*)d_out;

    char* w = (char*)d_ws;
    auto carve = [&](size_t nbytes) -> void* {
        void* p = (void*)w;
        w += (nbytes + 255) & ~(size_t)255;
        return p;
    };
    __half* Kh   = (__half*)carve((size_t)2 * NN * HH * 2);
    __half* Qh   = (__half*)carve((size_t)2 * NN * HH * 2);
    __half* Vh   = (__half*)carve((size_t)2 * NN * HH * 2);
    float* aggb  = (float*)carve((size_t)2 * NN * HH * 4);
    __half2* Emh2 = (__half2*)carve((size_t)NN * HH * 2);
    __half2* Edh2 = (__half2*)carve((size_t)NN * HH * 2);
    int* cnt     = (int*)carve((size_t)2 * NN * 4);    // cnt + sums: one memset
    float* sums  = (float*)carve((size_t)2 * 256 * 4);
    int* cur12   = (int*)carve((size_t)NN * 4);
    int* cur21   = (int*)carve((size_t)NN * 4);
    int* ptr12   = (int*)carve((size_t)(NN + 1) * 4);
    int* ptr21   = (int*)carve((size_t)(NN + 1) * 4);
    int2* rc12   = (int2*)carve((size_t)NE * 8);
    int2* rc21   = (int2*)carve((size_t)NE * 8);
    int* cnt12 = cnt;
    int* cnt21 = cnt + NN;

    // zero cnt + sums (adjacent carves) in one memset
    size_t zbytes = (((size_t)2 * NN * 4 + 255) & ~(size_t)255) + (size_t)2 * 256 * 4;
    hipMemsetAsync(cnt, 0, zbytes, stream);

    // CSR build
    int eb = (2 * NE + 255) / 256;
    count_kernel<<<(NE / 2 + 255) / 256, 256, 0, stream>>>(e12, e21, cnt12, cnt21);
    scan_kernel<<<2, 1024, 0, stream>>>(cnt12, cnt21, ptr12, ptr21, cur12, cur21);
    fill_kernel<<<eb, 256, 0, stream>>>(e12, e21, cur12, cur21, rc12, rc21);

    // input linear + relu fused with layer-0 K/Q/V (x lives only in LDS)
    in_kqv<<<dim3(NN / 16, 1, 2), 256, 0, stream>>>(
        x_n1, x_n2, Win, b_in, Wk, Wq, Wv, bk, bq, bv, Kh, Qh, Vh);

    conv_fused<<<dim3(NN / 8 * 2), 256, 0, stream>>>(
        ptr12, rc12, ptr21, rc21, Kh, Qh, Vh, aggb, sums, 0);

    // out GEMM layer 0 fused with layer-1 K/Q/V
    out_kqv<<<dim3(NN / 16, 1, 2), 256, 0, stream>>>(
        aggb, Wout, bout, sums, 0, Wk, Wq, Wv, bk, bq, bv, Kh, Qh, Vh, Emh2, Edh2);

    conv_fused<<<dim3(NN / 8 * 2), 256, 0, stream>>>(
        ptr12, rc12, ptr21, rc21, Kh, Qh, Vh, aggb, sums, 1);

    out_last<<<dim3(NN / 16, 1, 2), 256, 0, stream>>>(
        aggb, Wout, bout, sums, 1, Emh2, Edh2);

    pred_kernel<<<(NP * 8 + 255) / 256, 256, 0, stream>>>(
        (const __half*)Emh2, (const __half*)Edh2, pe, out);
}